// Round 11
// baseline (286.720 us; speedup 1.0000x reference)
//
#include <hip/hip_runtime.h>

#define N_NODES 100000
#define N_EDGES 600000

#define NBUCK 391                 // ceil(N_NODES/256) receiver/sender buckets
#define BROWS 512                 // padded bucket-row stride
#define NCHUNK 128                // blocks for hist/scatter passes
#define V4_TOTAL (N_EDGES / 4)    // 150000 int4
#define V4_CHUNK ((V4_TOTAL + NCHUNK - 1) / NCHUNK)

typedef __attribute__((ext_vector_type(8))) short short8;   // 8 bf16 (4 VGPRs)
typedef __attribute__((ext_vector_type(4))) float f32x4;    // MFMA accumulator

// round-to-nearest-even f32 -> bf16
__device__ inline unsigned short bf16r(float x) {
    unsigned u = __float_as_uint(x);
    return (unsigned short)((u + 0x7FFFu + ((u >> 16) & 1u)) >> 16);
}
__device__ inline unsigned bf16pack2(float x, float y) {
    unsigned ux = __float_as_uint(x), uy = __float_as_uint(y);
    ux = (ux + 0x7FFFu + ((ux >> 16) & 1u)) >> 16;
    uy = (uy + 0x7FFFu + ((uy >> 16) & 1u)) >> 16;
    return ux | (uy << 16);
}

// ---------------------------------------------------------------------------
// Fused weight prep: w0t/w1t = transposed bf16 of W0/W1 (128x128);
// wht[n][k], n<64 from Wmu, n>=64 from Wls (128 n x 256 k).
// ---------------------------------------------------------------------------
__global__ void prep_weights(const float* __restrict__ W0, const float* __restrict__ W1,
                             const float* __restrict__ Wmu, const float* __restrict__ Wls,
                             unsigned short* __restrict__ w0t, unsigned short* __restrict__ w1t,
                             unsigned short* __restrict__ wht) {
    int i = blockIdx.x * 256 + threadIdx.x;   // 0 .. 65535
    if (i < 16384) {
        int nn = i >> 7, k = i & 127;
        w0t[i] = bf16r(W0[k * 128 + nn]);
    } else if (i < 32768) {
        int j = i - 16384;
        int nn = j >> 7, k = j & 127;
        w1t[j] = bf16r(W1[k * 128 + nn]);
    } else {
        int j = i - 32768;
        int nn = j >> 8, k = j & 255;
        float v = (nn < 64) ? Wmu[k * 64 + nn] : Wls[k * 64 + (nn - 64)];
        wht[j] = bf16r(v);
    }
}

// ---------------------------------------------------------------------------
// 2-pass bucket counting sort, ALL atomics in LDS (r1-r4 evidence: memory-side
// fabric atomics ~60us floor; scope tricks don't help; redundant streaming
// worse). Every edge read O(1) times; coarse buckets (id>>8) fit LDS.
// ---------------------------------------------------------------------------
__global__ __launch_bounds__(1024)
void bucket_hist(const int* __restrict__ receivers, const int* __restrict__ senders,
                 int* __restrict__ hR, int* __restrict__ hS) {
    __shared__ int cR[BROWS], cS[BROWS];
    const int t = threadIdx.x;
    if (t < BROWS) { cR[t] = 0; cS[t] = 0; }
    __syncthreads();
    const int v0 = blockIdx.x * V4_CHUNK;
    const int v1 = min(v0 + V4_CHUNK, V4_TOTAL);
    for (int i = v0 + t; i < v1; i += 1024) {
        const int4 r = ((const int4*)receivers)[i];
        const int4 s = ((const int4*)senders)[i];
        atomicAdd(&cR[r.x >> 8], 1); atomicAdd(&cR[r.y >> 8], 1);
        atomicAdd(&cR[r.z >> 8], 1); atomicAdd(&cR[r.w >> 8], 1);
        atomicAdd(&cS[s.x >> 8], 1); atomicAdd(&cS[s.y >> 8], 1);
        atomicAdd(&cS[s.z >> 8], 1); atomicAdd(&cS[s.w >> 8], 1);
    }
    __syncthreads();
    if (t < BROWS) {
        hR[blockIdx.x * BROWS + t] = cR[t];
        hS[blockIdx.x * BROWS + t] = cS[t];
    }
}

// single block: bucket totals -> exclusive bucket bases; convert h matrices
// in place to global scatter cursors (base + per-block prefix within bucket)
__global__ __launch_bounds__(512)
void bucket_scan(int* __restrict__ hR, int* __restrict__ hS,
                 int* __restrict__ baseR, int* __restrict__ baseS) {
    __shared__ int a[BROWS], b[BROWS], a2[BROWS], b2[BROWS];
    const int t = threadIdx.x;
    int totR = 0, totS = 0;
    for (int blk = 0; blk < NCHUNK; ++blk) {
        totR += hR[blk * BROWS + t];
        totS += hS[blk * BROWS + t];
    }
    a[t] = totR; a2[t] = totS;
    __syncthreads();
    int* pin = a; int* pout = b; int* qin = a2; int* qout = b2;
    for (int off = 1; off < BROWS; off <<= 1) {
        pout[t] = pin[t] + ((t >= off) ? pin[t - off] : 0);
        qout[t] = qin[t] + ((t >= off) ? qin[t - off] : 0);
        __syncthreads();
        int* tmp = pin; pin = pout; pout = tmp;
        tmp = qin; qin = qout; qout = tmp;
    }
    const int bR = pin[t] - totR;     // exclusive
    const int bS = qin[t] - totS;
    if (t <= NBUCK) { baseR[t] = (t == NBUCK) ? N_EDGES : bR; }
    if (t <= NBUCK) { baseS[t] = (t == NBUCK) ? N_EDGES : bS; }
    int curR = bR, curS = bS;
    for (int blk = 0; blk < NCHUNK; ++blk) {
        const int vR = hR[blk * BROWS + t]; hR[blk * BROWS + t] = curR; curR += vR;
        const int vS = hS[blk * BROWS + t]; hS[blk * BROWS + t] = curS; curS += vS;
    }
}

__global__ __launch_bounds__(1024)
void bucket_scatter(const int* __restrict__ receivers, const int* __restrict__ senders,
                    const int* __restrict__ hR, const int* __restrict__ hS,
                    uint2* __restrict__ pairs, int* __restrict__ sbuf) {
    __shared__ int cR[BROWS], cS[BROWS];
    const int t = threadIdx.x;
    if (t < BROWS) {
        cR[t] = hR[blockIdx.x * BROWS + t];
        cS[t] = hS[blockIdx.x * BROWS + t];
    }
    __syncthreads();
    const int v0 = blockIdx.x * V4_CHUNK;
    const int v1 = min(v0 + V4_CHUNK, V4_TOTAL);
    for (int i = v0 + t; i < v1; i += 1024) {
        const int4 r = ((const int4*)receivers)[i];
        const int4 s = ((const int4*)senders)[i];
        int p;
        p = atomicAdd(&cR[r.x >> 8], 1); pairs[p] = make_uint2((unsigned)r.x, (unsigned)s.x);
        p = atomicAdd(&cR[r.y >> 8], 1); pairs[p] = make_uint2((unsigned)r.y, (unsigned)s.y);
        p = atomicAdd(&cR[r.z >> 8], 1); pairs[p] = make_uint2((unsigned)r.z, (unsigned)s.z);
        p = atomicAdd(&cR[r.w >> 8], 1); pairs[p] = make_uint2((unsigned)r.w, (unsigned)s.w);
        p = atomicAdd(&cS[s.x >> 8], 1); sbuf[p] = s.x;
        p = atomicAdd(&cS[s.y >> 8], 1); sbuf[p] = s.y;
        p = atomicAdd(&cS[s.z >> 8], 1); sbuf[p] = s.z;
        p = atomicAdd(&cS[s.w >> 8], 1); sbuf[p] = s.w;
    }
}

// one block per receiver bucket (256 nodes, ~1.5k edges): LDS count -> LDS
// scan -> offs/inv_r, then LDS-cursor scatter of senders into srt.
__global__ __launch_bounds__(256)
void bucket_finalize(const uint2* __restrict__ pairs, const int* __restrict__ baseR,
                     int* __restrict__ offs, int* __restrict__ srt,
                     float* __restrict__ inv_r, int n) {
    __shared__ int cnt[256], cur[256];
    __shared__ int sa[256], sb[256];
    const int t = threadIdx.x;
    const int b = blockIdx.x;
    const int e0 = baseR[b], e1 = baseR[b + 1];
    cnt[t] = 0;
    __syncthreads();
    for (int i = e0 + t; i < e1; i += 256)
        atomicAdd(&cnt[pairs[i].x & 255u], 1);
    __syncthreads();
    const int v = cnt[t];
    sa[t] = v;
    __syncthreads();
    int* pin = sa; int* pout = sb;
    for (int off = 1; off < 256; off <<= 1) {
        pout[t] = pin[t] + ((t >= off) ? pin[t - off] : 0);
        __syncthreads();
        int* tmp = pin; pin = pout; pout = tmp;
    }
    cur[t] = pin[t] - v;              // exclusive local offset (= running cursor)
    const int node = (b << 8) + t;
    if (node < n) {
        offs[node] = e0 + pin[t] - v;
        inv_r[node] = rsqrtf(fmaxf((float)v, 1.0f));
    }
    if (b == 0 && t == 0) offs[n] = N_EDGES;
    __syncthreads();
    for (int i = e0 + t; i < e1; i += 256) {
        const uint2 pr = pairs[i];
        const int p = atomicAdd(&cur[pr.x & 255u], 1);
        srt[e0 + p] = (int)pr.y;
    }
}

__global__ __launch_bounds__(256)
void sender_count(const int* __restrict__ sbuf, const int* __restrict__ baseS,
                  float* __restrict__ inv_s, int n) {
    __shared__ int cnt[256];
    const int t = threadIdx.x;
    const int b = blockIdx.x;
    const int e0 = baseS[b], e1 = baseS[b + 1];
    cnt[t] = 0;
    __syncthreads();
    for (int i = e0 + t; i < e1; i += 256)
        atomicAdd(&cnt[sbuf[i] & 255], 1);
    __syncthreads();
    const int node = (b << 8) + t;
    if (node < n) inv_s[node] = rsqrtf(fmaxf((float)cnt[t], 1.0f));
}

// ---------------------------------------------------------------------------
// dst[r] = bf16( scale[r] * sum over incoming edges of src[sender] )
// ---------------------------------------------------------------------------
__global__ __launch_bounds__(256)
void aggregate_kernel(const uint4* __restrict__ src, uint4* __restrict__ dst,
                      const int* __restrict__ offs, const int* __restrict__ srt,
                      const float* __restrict__ scale, int n) {
    const int lane = threadIdx.x & 63;
    const int wave = threadIdx.x >> 6;
    const int grp  = lane >> 4;          // 0..3 (receiver group within wave)
    const int l16  = lane & 15;
    const int wid  = blockIdx.x * 4 + wave;      // wave index
    const int nwv  = gridDim.x * 4;              // total waves
    const unsigned grpbase = lane & 48;          // grp*16, for shfl source

    for (int rb = wid * 4; rb < n; rb += nwv * 4) {   // wave-uniform
        const int r = rb + grp;
        const bool valid = (r < n);
        int beg = 0, deg = 0;
        if (valid) { beg = offs[r]; deg = offs[r + 1] - beg; }
        float ax[8];
        #pragma unroll
        for (int k = 0; k < 8; ++k) ax[k] = 0.0f;

        for (int j0 = 0; ; j0 += 16) {
            const int rem = deg - j0;            // group-uniform
            int wm = rem;                        // wave max remaining
            wm = max(wm, __shfl_xor(wm, 16));
            wm = max(wm, __shfl_xor(wm, 32));
            if (wm <= 0) break;
            const int idx = (j0 + l16 < deg) ? srt[beg + j0 + l16] : 0;
            const int jmax = (wm < 16) ? wm : 16;
            for (int j = 0; j < jmax; j += 8) {
                uint4 v[8];
                #pragma unroll
                for (int k = 0; k < 8; ++k) {
                    const int s = __shfl(idx, grpbase + j + k);
                    v[k] = make_uint4(0u, 0u, 0u, 0u);
                    if (j + k < rem) v[k] = src[(size_t)s * 16 + l16];
                }
                #pragma unroll
                for (int k = 0; k < 8; ++k) {
                    ax[0] += __uint_as_float(v[k].x << 16);
                    ax[1] += __uint_as_float(v[k].x & 0xFFFF0000u);
                    ax[2] += __uint_as_float(v[k].y << 16);
                    ax[3] += __uint_as_float(v[k].y & 0xFFFF0000u);
                    ax[4] += __uint_as_float(v[k].z << 16);
                    ax[5] += __uint_as_float(v[k].z & 0xFFFF0000u);
                    ax[6] += __uint_as_float(v[k].w << 16);
                    ax[7] += __uint_as_float(v[k].w & 0xFFFF0000u);
                }
            }
        }
        if (valid) {
            const float sc = scale[r];
            uint4 o;
            o.x = bf16pack2(ax[0] * sc, ax[1] * sc);
            o.y = bf16pack2(ax[2] * sc, ax[3] * sc);
            o.z = bf16pack2(ax[4] * sc, ax[5] * sc);
            o.w = bf16pack2(ax[6] * sc, ax[7] * sc);
            dst[(size_t)r * 16 + l16] = o;
        }
    }
}

// ---------------------------------------------------------------------------
// MFMA graph-conv layer: y = bf16( softmax(relu(x @ W + b)) * inv_out )
// r9 structure (validated: 41.5 -> ~20us): A direct-from-global into fragment
// registers; B (Wt) staged once per block in LDS (padded stride 136);
// wave-local softmax, no max-subtract; Wl reused for coalesced output stage.
// ---------------------------------------------------------------------------
template<bool IN_BF16>
__global__ __launch_bounds__(256)
void gc_mfma(const void* __restrict__ xv, const unsigned short* __restrict__ Wt,
             const float* __restrict__ bias, const float* __restrict__ inv_out,
             unsigned short* __restrict__ y, int nrows) {
    __shared__ unsigned short Wl[128 * 136];   // B tile; later reused for output
    __shared__ float sinv[64];
    const int row0 = blockIdx.x * 64;

    const int lane = threadIdx.x & 63;
    const int w = threadIdx.x >> 6;      // wave owns rows w*16 .. w*16+15
    const int q = lane >> 4;
    const int l16 = lane & 15;
    const int grow = row0 + w * 16 + l16;   // row this lane loads A from
    const bool rv = (grow < nrows);

    // A fragments direct from global (no LDS) - issue before staging barrier
    short8 af[4];
    if (IN_BF16) {
        const unsigned short* x = (const unsigned short*)xv;
        #pragma unroll
        for (int k0 = 0; k0 < 4; ++k0) {
            short8 z = {0, 0, 0, 0, 0, 0, 0, 0};
            if (rv) z = *(const short8*)&x[(size_t)grow * 128 + k0 * 32 + q * 8];
            af[k0] = z;
        }
    } else {
        const float* x = (const float*)xv;
        #pragma unroll
        for (int k0 = 0; k0 < 4; ++k0) {
            float4 a = make_float4(0.f, 0.f, 0.f, 0.f);
            float4 b = make_float4(0.f, 0.f, 0.f, 0.f);
            if (rv) {
                a = *(const float4*)&x[(size_t)grow * 128 + k0 * 32 + q * 8];
                b = *(const float4*)&x[(size_t)grow * 128 + k0 * 32 + q * 8 + 4];
            }
            uint4 u = make_uint4(bf16pack2(a.x, a.y), bf16pack2(a.z, a.w),
                                 bf16pack2(b.x, b.y), bf16pack2(b.z, b.w));
            af[k0] = *(short8*)&u;
        }
    }

    if (threadIdx.x < 64) {
        int g = row0 + threadIdx.x;
        sinv[threadIdx.x] = (g < nrows) ? inv_out[g] : 1.0f;
    }

    // stage Wt (128 x 128 bf16) into LDS, padded row stride 136
    for (int i = threadIdx.x; i < 128 * 16; i += 256) {
        int r = i >> 4, c = i & 15;
        *(uint4*)&Wl[r * 136 + c * 8] = *(const uint4*)&Wt[r * 128 + c * 8];
    }
    __syncthreads();

    f32x4 acc[8] = {};                   // 8 col-blocks of 16
    #pragma unroll
    for (int nt = 0; nt < 8; ++nt) {
        #pragma unroll
        for (int k0 = 0; k0 < 4; ++k0) {
            short8 b = *(const short8*)&Wl[(nt * 16 + l16) * 136 + k0 * 32 + q * 8];
            acc[nt] = __builtin_amdgcn_mfma_f32_16x16x32_bf16(af[k0], b, acc[nt], 0, 0, 0);
        }
    }

    // bias -> relu -> exp (no max-subtract: relu-bounded) -> wave-local row sum
    float e[8][4];
    float s[4] = {0.f, 0.f, 0.f, 0.f};
    #pragma unroll
    for (int nt = 0; nt < 8; ++nt) {
        const float bv = bias[nt * 16 + l16];
        #pragma unroll
        for (int r = 0; r < 4; ++r) {
            float ev = __expf(fmaxf(acc[nt][r] + bv, 0.0f));
            e[nt][r] = ev;
            s[r] += ev;
        }
    }
    #pragma unroll
    for (int off = 1; off < 16; off <<= 1)
        #pragma unroll
        for (int r = 0; r < 4; ++r)
            s[r] += __shfl_xor(s[r], off);

    __syncthreads();                     // all B reads done; Wl reusable

    // scale and stage bf16 output (rows w*16+q*4+r) into Wl
    #pragma unroll
    for (int r = 0; r < 4; ++r) {
        const int rl = w * 16 + q * 4 + r;
        const float sc = sinv[rl] / s[r];
        #pragma unroll
        for (int nt = 0; nt < 8; ++nt)
            Wl[rl * 136 + nt * 16 + l16] = bf16r(e[nt][r] * sc);
    }
    __syncthreads();

    // coalesced uint4 stores: 64 rows x 16 uint4
    for (int c = threadIdx.x; c < 64 * 16; c += 256) {
        int r = c >> 4, cu = c & 15;
        int g = row0 + r;
        if (g < nrows) {
            uint4 vv = *(const uint4*)&Wl[r * 136 + cu * 8];
            *(uint4*)&y[(size_t)g * 128 + cu * 8] = vv;
        }
    }
}

// ---------------------------------------------------------------------------
// Fused heads: out = [mu | logsig2], X = concat(h, nodes) [rows x 256 k].
// Round-10: r9 recipe applied. Wave owns 16 rows x all 128 output cols
// (64 mu + 64 ls). A fragments DIRECT from global: k0<4 = short8 from h,
// k0>=4 = float4-pair from nodes packed to bf16 (no input LDS/barrier).
// B (wht, 128n x 256k = 64KB) staged once per block in LDS, padded stride
// 264 (bank-step 4/lane = free 2-way aliasing). 64 MFMAs/wave.
// ---------------------------------------------------------------------------
__global__ __launch_bounds__(256)
void head_mfma(const unsigned short* __restrict__ h, const float* __restrict__ nodes,
               const unsigned short* __restrict__ Wt,
               const float* __restrict__ bmu, const float* __restrict__ bls,
               float* __restrict__ out, int nrows) {
    __shared__ unsigned short Wl[128 * 264];   // 64KB B tile
    const int row0 = blockIdx.x * 64;

    const int lane = threadIdx.x & 63;
    const int w = threadIdx.x >> 6;      // wave owns rows w*16 .. w*16+15
    const int q = lane >> 4;
    const int l16 = lane & 15;
    const int grow = row0 + w * 16 + l16;
    const bool rv = (grow < nrows);

    // A fragments direct from global: 8 K-slices of 32 (h cols 0..127, nodes 128..255)
    short8 af[8];
    #pragma unroll
    for (int k0 = 0; k0 < 4; ++k0) {
        short8 z = {0, 0, 0, 0, 0, 0, 0, 0};
        if (rv) z = *(const short8*)&h[(size_t)grow * 128 + k0 * 32 + q * 8];
        af[k0] = z;
    }
    #pragma unroll
    for (int k0 = 0; k0 < 4; ++k0) {
        float4 a = make_float4(0.f, 0.f, 0.f, 0.f);
        float4 b = make_float4(0.f, 0.f, 0.f, 0.f);
        if (rv) {
            a = *(const float4*)&nodes[(size_t)grow * 128 + k0 * 32 + q * 8];
            b = *(const float4*)&nodes[(size_t)grow * 128 + k0 * 32 + q * 8 + 4];
        }
        uint4 u = make_uint4(bf16pack2(a.x, a.y), bf16pack2(a.z, a.w),
                             bf16pack2(b.x, b.y), bf16pack2(b.z, b.w));
        af[4 + k0] = *(short8*)&u;
    }

    // stage wht (128 n x 256 k bf16, 64KB) into LDS, padded stride 264
    for (int i = threadIdx.x; i < 128 * 32; i += 256) {
        int r = i >> 5, c = i & 31;
        *(uint4*)&Wl[r * 264 + c * 8] = *(const uint4*)&Wt[r * 256 + c * 8];
    }
    __syncthreads();

    f32x4 acc[8] = {};                   // 8 output col-blocks of 16
    #pragma unroll
    for (int nt = 0; nt < 8; ++nt) {
        #pragma unroll
        for (int k0 = 0; k0 < 8; ++k0) {
            short8 b = *(const short8*)&Wl[(nt * 16 + l16) * 264 + k0 * 32 + q * 8];
            acc[nt] = __builtin_amdgcn_mfma_f32_16x16x32_bf16(af[k0], b, acc[nt], 0, 0, 0);
        }
    }

    // bias per col-block: nt<4 -> mu cols nt*16+l16 ; nt>=4 -> ls cols
    float bv[8];
    #pragma unroll
    for (int nt = 0; nt < 4; ++nt) bv[nt] = bmu[nt * 16 + l16];
    #pragma unroll
    for (int nt = 4; nt < 8; ++nt) bv[nt] = bls[(nt - 4) * 16 + l16];

    float* const omu = out;
    float* const ols = out + (size_t)nrows * 64;
    #pragma unroll
    for (int r = 0; r < 4; ++r) {
        const int g = row0 + w * 16 + q * 4 + r;
        if (g < nrows) {
            #pragma unroll
            for (int nt = 0; nt < 4; ++nt)
                omu[(size_t)g * 64 + nt * 16 + l16] = acc[nt][r] + bv[nt];
            #pragma unroll
            for (int nt = 4; nt < 8; ++nt)
                ols[(size_t)g * 64 + (nt - 4) * 16 + l16] = acc[nt][r] + bv[nt];
        }
    }
}

extern "C" void kernel_launch(void* const* d_in, const int* in_sizes, int n_in,
                              void* d_out, int out_size, void* d_ws, size_t ws_size,
                              hipStream_t stream) {
    const float* nodes     = (const float*)d_in[0];
    const int*   senders   = (const int*)d_in[1];
    const int*   receivers = (const int*)d_in[2];
    const float* W0  = (const float*)d_in[3];
    const float* b0  = (const float*)d_in[4];
    const float* W1  = (const float*)d_in[5];
    const float* b1  = (const float*)d_in[6];
    const float* Wmu = (const float*)d_in[7];
    const float* bmu = (const float*)d_in[8];
    const float* Wls = (const float*)d_in[9];
    const float* bls = (const float*)d_in[10];
    float* out = (float*)d_out;

    const int N = N_NODES;
    const int NT64 = (N + 63) / 64;      // 64-row tiles

    // ws: inv_s[N] f32 | inv_r[N] f32 | buf0[N*128] bf16 | buf1[N*128] bf16 | weights
    float* inv_s = (float*)d_ws;
    float* inv_r = inv_s + N;
    unsigned short* buf0 = (unsigned short*)(inv_r + N);
    unsigned short* buf1 = buf0 + (size_t)N * 128;
    unsigned short* w0t  = buf1 + (size_t)N * 128;
    unsigned short* w1t  = w0t + 128 * 128;
    unsigned short* wht  = w1t + 128 * 128;

    // sort metadata in d_out (scratch until heads write it): offs[N+1] | srt[E]
    int* offs = (int*)d_out;
    int* srt  = offs + (N + 1);

    // setup-only temps alias buf0 (dead before layer-1 writes buf0):
    // pairs[E] uint2 | sbuf[E] | hR[NCHUNK*BROWS] | hS | baseR[512] | baseS[512]
    uint2* pairs = (uint2*)buf0;
    int* sbuf  = (int*)(pairs + N_EDGES);
    int* hR    = sbuf + N_EDGES;
    int* hS    = hR + NCHUNK * BROWS;
    int* baseR = hS + NCHUNK * BROWS;
    int* baseS = baseR + 512;

    // --- weight prep (bf16 transposed, one launch) ---
    prep_weights<<<256, 256, 0, stream>>>(W0, W1, Wmu, Wls, w0t, w1t, wht);

    // --- counting sort of edges by receiver + degrees (all atomics in LDS) ---
    bucket_hist<<<NCHUNK, 1024, 0, stream>>>(receivers, senders, hR, hS);
    bucket_scan<<<1, 512, 0, stream>>>(hR, hS, baseR, baseS);
    bucket_scatter<<<NCHUNK, 1024, 0, stream>>>(receivers, senders, hR, hS, pairs, sbuf);
    bucket_finalize<<<NBUCK, 256, 0, stream>>>(pairs, baseR, offs, srt, inv_r, N);
    sender_count<<<NBUCK, 256, 0, stream>>>(sbuf, baseS, inv_s, N);

    // --- layer 1 ---
    gc_mfma<false><<<NT64, 256, 0, stream>>>(nodes, w0t, b0, inv_s, buf0, N);
    aggregate_kernel<<<2048, 256, 0, stream>>>((const uint4*)buf0, (uint4*)buf1,
                                               offs, srt, inv_r, N);

    // --- layer 2 (input pre-scaled bf16) ---
    gc_mfma<true><<<NT64, 256, 0, stream>>>(buf1, w1t, b1, inv_s, buf0, N);
    aggregate_kernel<<<2048, 256, 0, stream>>>((const uint4*)buf0, (uint4*)buf1,
                                               offs, srt, inv_r, N);

    // --- fused heads: out = [mu | logsig2] ---
    head_mfma<<<NT64, 256, 0, stream>>>(buf1, nodes, wht, bmu, bls, out, N);
}

// Round 12
// 270.477 us; speedup vs baseline: 1.0601x; 1.0601x over previous
//
#include <hip/hip_runtime.h>

#define N_NODES 100000
#define N_EDGES 600000

#define NBUCK 391                 // ceil(N_NODES/256) receiver/sender buckets
#define BROWS 512                 // padded bucket-row stride
#define NCHUNK 128                // blocks for hist/scatter passes
#define V4_TOTAL (N_EDGES / 4)    // 150000 int4
#define V4_CHUNK ((V4_TOTAL + NCHUNK - 1) / NCHUNK)

typedef __attribute__((ext_vector_type(8))) short short8;   // 8 bf16 (4 VGPRs)
typedef __attribute__((ext_vector_type(4))) float f32x4;    // MFMA accumulator

// round-to-nearest-even f32 -> bf16
__device__ inline unsigned short bf16r(float x) {
    unsigned u = __float_as_uint(x);
    return (unsigned short)((u + 0x7FFFu + ((u >> 16) & 1u)) >> 16);
}
__device__ inline unsigned bf16pack2(float x, float y) {
    unsigned ux = __float_as_uint(x), uy = __float_as_uint(y);
    ux = (ux + 0x7FFFu + ((ux >> 16) & 1u)) >> 16;
    uy = (uy + 0x7FFFu + ((uy >> 16) & 1u)) >> 16;
    return ux | (uy << 16);
}

// ---------------------------------------------------------------------------
// Fused weight prep: w0t/w1t = transposed bf16 of W0/W1 (128x128);
// wht[n][k], n<64 from Wmu, n>=64 from Wls (128 n x 256 k).
// ---------------------------------------------------------------------------
__global__ void prep_weights(const float* __restrict__ W0, const float* __restrict__ W1,
                             const float* __restrict__ Wmu, const float* __restrict__ Wls,
                             unsigned short* __restrict__ w0t, unsigned short* __restrict__ w1t,
                             unsigned short* __restrict__ wht) {
    int i = blockIdx.x * 256 + threadIdx.x;   // 0 .. 65535
    if (i < 16384) {
        int nn = i >> 7, k = i & 127;
        w0t[i] = bf16r(W0[k * 128 + nn]);
    } else if (i < 32768) {
        int j = i - 16384;
        int nn = j >> 7, k = j & 127;
        w1t[j] = bf16r(W1[k * 128 + nn]);
    } else {
        int j = i - 32768;
        int nn = j >> 8, k = j & 255;
        float v = (nn < 64) ? Wmu[k * 64 + nn] : Wls[k * 64 + (nn - 64)];
        wht[j] = bf16r(v);
    }
}

// ---------------------------------------------------------------------------
// 2-pass bucket counting sort, ALL atomics in LDS (r1-r4 evidence: memory-side
// fabric atomics ~60us floor; scope tricks don't help; redundant streaming
// worse). Every edge read O(1) times; coarse buckets (id>>8) fit LDS.
// ---------------------------------------------------------------------------
__global__ __launch_bounds__(1024)
void bucket_hist(const int* __restrict__ receivers, const int* __restrict__ senders,
                 int* __restrict__ hR, int* __restrict__ hS) {
    __shared__ int cR[BROWS], cS[BROWS];
    const int t = threadIdx.x;
    if (t < BROWS) { cR[t] = 0; cS[t] = 0; }
    __syncthreads();
    const int v0 = blockIdx.x * V4_CHUNK;
    const int v1 = min(v0 + V4_CHUNK, V4_TOTAL);
    for (int i = v0 + t; i < v1; i += 1024) {
        const int4 r = ((const int4*)receivers)[i];
        const int4 s = ((const int4*)senders)[i];
        atomicAdd(&cR[r.x >> 8], 1); atomicAdd(&cR[r.y >> 8], 1);
        atomicAdd(&cR[r.z >> 8], 1); atomicAdd(&cR[r.w >> 8], 1);
        atomicAdd(&cS[s.x >> 8], 1); atomicAdd(&cS[s.y >> 8], 1);
        atomicAdd(&cS[s.z >> 8], 1); atomicAdd(&cS[s.w >> 8], 1);
    }
    __syncthreads();
    if (t < BROWS) {
        hR[blockIdx.x * BROWS + t] = cR[t];
        hS[blockIdx.x * BROWS + t] = cS[t];
    }
}

// single block: bucket totals -> exclusive bucket bases; convert h matrices
// in place to global scatter cursors (base + per-block prefix within bucket)
__global__ __launch_bounds__(512)
void bucket_scan(int* __restrict__ hR, int* __restrict__ hS,
                 int* __restrict__ baseR, int* __restrict__ baseS) {
    __shared__ int a[BROWS], b[BROWS], a2[BROWS], b2[BROWS];
    const int t = threadIdx.x;
    int totR = 0, totS = 0;
    for (int blk = 0; blk < NCHUNK; ++blk) {
        totR += hR[blk * BROWS + t];
        totS += hS[blk * BROWS + t];
    }
    a[t] = totR; a2[t] = totS;
    __syncthreads();
    int* pin = a; int* pout = b; int* qin = a2; int* qout = b2;
    for (int off = 1; off < BROWS; off <<= 1) {
        pout[t] = pin[t] + ((t >= off) ? pin[t - off] : 0);
        qout[t] = qin[t] + ((t >= off) ? qin[t - off] : 0);
        __syncthreads();
        int* tmp = pin; pin = pout; pout = tmp;
        tmp = qin; qin = qout; qout = tmp;
    }
    const int bR = pin[t] - totR;     // exclusive
    const int bS = qin[t] - totS;
    if (t <= NBUCK) { baseR[t] = (t == NBUCK) ? N_EDGES : bR; }
    if (t <= NBUCK) { baseS[t] = (t == NBUCK) ? N_EDGES : bS; }
    int curR = bR, curS = bS;
    for (int blk = 0; blk < NCHUNK; ++blk) {
        const int vR = hR[blk * BROWS + t]; hR[blk * BROWS + t] = curR; curR += vR;
        const int vS = hS[blk * BROWS + t]; hS[blk * BROWS + t] = curS; curS += vS;
    }
}

__global__ __launch_bounds__(1024)
void bucket_scatter(const int* __restrict__ receivers, const int* __restrict__ senders,
                    const int* __restrict__ hR, const int* __restrict__ hS,
                    uint2* __restrict__ pairs, int* __restrict__ sbuf) {
    __shared__ int cR[BROWS], cS[BROWS];
    const int t = threadIdx.x;
    if (t < BROWS) {
        cR[t] = hR[blockIdx.x * BROWS + t];
        cS[t] = hS[blockIdx.x * BROWS + t];
    }
    __syncthreads();
    const int v0 = blockIdx.x * V4_CHUNK;
    const int v1 = min(v0 + V4_CHUNK, V4_TOTAL);
    for (int i = v0 + t; i < v1; i += 1024) {
        const int4 r = ((const int4*)receivers)[i];
        const int4 s = ((const int4*)senders)[i];
        int p;
        p = atomicAdd(&cR[r.x >> 8], 1); pairs[p] = make_uint2((unsigned)r.x, (unsigned)s.x);
        p = atomicAdd(&cR[r.y >> 8], 1); pairs[p] = make_uint2((unsigned)r.y, (unsigned)s.y);
        p = atomicAdd(&cR[r.z >> 8], 1); pairs[p] = make_uint2((unsigned)r.z, (unsigned)s.z);
        p = atomicAdd(&cR[r.w >> 8], 1); pairs[p] = make_uint2((unsigned)r.w, (unsigned)s.w);
        p = atomicAdd(&cS[s.x >> 8], 1); sbuf[p] = s.x;
        p = atomicAdd(&cS[s.y >> 8], 1); sbuf[p] = s.y;
        p = atomicAdd(&cS[s.z >> 8], 1); sbuf[p] = s.z;
        p = atomicAdd(&cS[s.w >> 8], 1); sbuf[p] = s.w;
    }
}

// one block per receiver bucket (256 nodes, ~1.5k edges): LDS count -> LDS
// scan -> offs/inv_r, then LDS-cursor scatter of senders into srt.
__global__ __launch_bounds__(256)
void bucket_finalize(const uint2* __restrict__ pairs, const int* __restrict__ baseR,
                     int* __restrict__ offs, int* __restrict__ srt,
                     float* __restrict__ inv_r, int n) {
    __shared__ int cnt[256], cur[256];
    __shared__ int sa[256], sb[256];
    const int t = threadIdx.x;
    const int b = blockIdx.x;
    const int e0 = baseR[b], e1 = baseR[b + 1];
    cnt[t] = 0;
    __syncthreads();
    for (int i = e0 + t; i < e1; i += 256)
        atomicAdd(&cnt[pairs[i].x & 255u], 1);
    __syncthreads();
    const int v = cnt[t];
    sa[t] = v;
    __syncthreads();
    int* pin = sa; int* pout = sb;
    for (int off = 1; off < 256; off <<= 1) {
        pout[t] = pin[t] + ((t >= off) ? pin[t - off] : 0);
        __syncthreads();
        int* tmp = pin; pin = pout; pout = tmp;
    }
    cur[t] = pin[t] - v;              // exclusive local offset (= running cursor)
    const int node = (b << 8) + t;
    if (node < n) {
        offs[node] = e0 + pin[t] - v;
        inv_r[node] = rsqrtf(fmaxf((float)v, 1.0f));
    }
    if (b == 0 && t == 0) offs[n] = N_EDGES;
    __syncthreads();
    for (int i = e0 + t; i < e1; i += 256) {
        const uint2 pr = pairs[i];
        const int p = atomicAdd(&cur[pr.x & 255u], 1);
        srt[e0 + p] = (int)pr.y;
    }
}

__global__ __launch_bounds__(256)
void sender_count(const int* __restrict__ sbuf, const int* __restrict__ baseS,
                  float* __restrict__ inv_s, int n) {
    __shared__ int cnt[256];
    const int t = threadIdx.x;
    const int b = blockIdx.x;
    const int e0 = baseS[b], e1 = baseS[b + 1];
    cnt[t] = 0;
    __syncthreads();
    for (int i = e0 + t; i < e1; i += 256)
        atomicAdd(&cnt[sbuf[i] & 255], 1);
    __syncthreads();
    const int node = (b << 8) + t;
    if (node < n) inv_s[node] = rsqrtf(fmaxf((float)cnt[t], 1.0f));
}

// ---------------------------------------------------------------------------
// dst[r] = bf16( scale[r] * sum over incoming edges of src[sender] )
// ---------------------------------------------------------------------------
__global__ __launch_bounds__(256)
void aggregate_kernel(const uint4* __restrict__ src, uint4* __restrict__ dst,
                      const int* __restrict__ offs, const int* __restrict__ srt,
                      const float* __restrict__ scale, int n) {
    const int lane = threadIdx.x & 63;
    const int wave = threadIdx.x >> 6;
    const int grp  = lane >> 4;          // 0..3 (receiver group within wave)
    const int l16  = lane & 15;
    const int wid  = blockIdx.x * 4 + wave;      // wave index
    const int nwv  = gridDim.x * 4;              // total waves
    const unsigned grpbase = lane & 48;          // grp*16, for shfl source

    for (int rb = wid * 4; rb < n; rb += nwv * 4) {   // wave-uniform
        const int r = rb + grp;
        const bool valid = (r < n);
        int beg = 0, deg = 0;
        if (valid) { beg = offs[r]; deg = offs[r + 1] - beg; }
        float ax[8];
        #pragma unroll
        for (int k = 0; k < 8; ++k) ax[k] = 0.0f;

        for (int j0 = 0; ; j0 += 16) {
            const int rem = deg - j0;            // group-uniform
            int wm = rem;                        // wave max remaining
            wm = max(wm, __shfl_xor(wm, 16));
            wm = max(wm, __shfl_xor(wm, 32));
            if (wm <= 0) break;
            const int idx = (j0 + l16 < deg) ? srt[beg + j0 + l16] : 0;
            const int jmax = (wm < 16) ? wm : 16;
            for (int j = 0; j < jmax; j += 8) {
                uint4 v[8];
                #pragma unroll
                for (int k = 0; k < 8; ++k) {
                    const int s = __shfl(idx, grpbase + j + k);
                    v[k] = make_uint4(0u, 0u, 0u, 0u);
                    if (j + k < rem) v[k] = src[(size_t)s * 16 + l16];
                }
                #pragma unroll
                for (int k = 0; k < 8; ++k) {
                    ax[0] += __uint_as_float(v[k].x << 16);
                    ax[1] += __uint_as_float(v[k].x & 0xFFFF0000u);
                    ax[2] += __uint_as_float(v[k].y << 16);
                    ax[3] += __uint_as_float(v[k].y & 0xFFFF0000u);
                    ax[4] += __uint_as_float(v[k].z << 16);
                    ax[5] += __uint_as_float(v[k].z & 0xFFFF0000u);
                    ax[6] += __uint_as_float(v[k].w << 16);
                    ax[7] += __uint_as_float(v[k].w & 0xFFFF0000u);
                }
            }
        }
        if (valid) {
            const float sc = scale[r];
            uint4 o;
            o.x = bf16pack2(ax[0] * sc, ax[1] * sc);
            o.y = bf16pack2(ax[2] * sc, ax[3] * sc);
            o.z = bf16pack2(ax[4] * sc, ax[5] * sc);
            o.w = bf16pack2(ax[6] * sc, ax[7] * sc);
            dst[(size_t)r * 16 + l16] = o;
        }
    }
}

// ---------------------------------------------------------------------------
// MFMA graph-conv layer: y = bf16( softmax(relu(x @ W + b)) * inv_out )
// r9 structure (validated: 41.5 -> ~20us): A direct-from-global into fragment
// registers; B (Wt) staged once per block in LDS (padded stride 136);
// wave-local softmax, no max-subtract; Wl reused for coalesced output stage.
// ---------------------------------------------------------------------------
template<bool IN_BF16>
__global__ __launch_bounds__(256)
void gc_mfma(const void* __restrict__ xv, const unsigned short* __restrict__ Wt,
             const float* __restrict__ bias, const float* __restrict__ inv_out,
             unsigned short* __restrict__ y, int nrows) {
    __shared__ unsigned short Wl[128 * 136];   // B tile; later reused for output
    __shared__ float sinv[64];
    const int row0 = blockIdx.x * 64;

    const int lane = threadIdx.x & 63;
    const int w = threadIdx.x >> 6;      // wave owns rows w*16 .. w*16+15
    const int q = lane >> 4;
    const int l16 = lane & 15;
    const int grow = row0 + w * 16 + l16;   // row this lane loads A from
    const bool rv = (grow < nrows);

    // A fragments direct from global (no LDS) - issue before staging barrier
    short8 af[4];
    if (IN_BF16) {
        const unsigned short* x = (const unsigned short*)xv;
        #pragma unroll
        for (int k0 = 0; k0 < 4; ++k0) {
            short8 z = {0, 0, 0, 0, 0, 0, 0, 0};
            if (rv) z = *(const short8*)&x[(size_t)grow * 128 + k0 * 32 + q * 8];
            af[k0] = z;
        }
    } else {
        const float* x = (const float*)xv;
        #pragma unroll
        for (int k0 = 0; k0 < 4; ++k0) {
            float4 a = make_float4(0.f, 0.f, 0.f, 0.f);
            float4 b = make_float4(0.f, 0.f, 0.f, 0.f);
            if (rv) {
                a = *(const float4*)&x[(size_t)grow * 128 + k0 * 32 + q * 8];
                b = *(const float4*)&x[(size_t)grow * 128 + k0 * 32 + q * 8 + 4];
            }
            uint4 u = make_uint4(bf16pack2(a.x, a.y), bf16pack2(a.z, a.w),
                                 bf16pack2(b.x, b.y), bf16pack2(b.z, b.w));
            af[k0] = *(short8*)&u;
        }
    }

    if (threadIdx.x < 64) {
        int g = row0 + threadIdx.x;
        sinv[threadIdx.x] = (g < nrows) ? inv_out[g] : 1.0f;
    }

    // stage Wt (128 x 128 bf16) into LDS, padded row stride 136
    for (int i = threadIdx.x; i < 128 * 16; i += 256) {
        int r = i >> 4, c = i & 15;
        *(uint4*)&Wl[r * 136 + c * 8] = *(const uint4*)&Wt[r * 128 + c * 8];
    }
    __syncthreads();

    f32x4 acc[8] = {};                   // 8 col-blocks of 16
    #pragma unroll
    for (int nt = 0; nt < 8; ++nt) {
        #pragma unroll
        for (int k0 = 0; k0 < 4; ++k0) {
            short8 b = *(const short8*)&Wl[(nt * 16 + l16) * 136 + k0 * 32 + q * 8];
            acc[nt] = __builtin_amdgcn_mfma_f32_16x16x32_bf16(af[k0], b, acc[nt], 0, 0, 0);
        }
    }

    // bias -> relu -> exp (no max-subtract: relu-bounded) -> wave-local row sum
    float e[8][4];
    float s[4] = {0.f, 0.f, 0.f, 0.f};
    #pragma unroll
    for (int nt = 0; nt < 8; ++nt) {
        const float bv = bias[nt * 16 + l16];
        #pragma unroll
        for (int r = 0; r < 4; ++r) {
            float ev = __expf(fmaxf(acc[nt][r] + bv, 0.0f));
            e[nt][r] = ev;
            s[r] += ev;
        }
    }
    #pragma unroll
    for (int off = 1; off < 16; off <<= 1)
        #pragma unroll
        for (int r = 0; r < 4; ++r)
            s[r] += __shfl_xor(s[r], off);

    __syncthreads();                     // all B reads done; Wl reusable

    // scale and stage bf16 output (rows w*16+q*4+r) into Wl
    #pragma unroll
    for (int r = 0; r < 4; ++r) {
        const int rl = w * 16 + q * 4 + r;
        const float sc = sinv[rl] / s[r];
        #pragma unroll
        for (int nt = 0; nt < 8; ++nt)
            Wl[rl * 136 + nt * 16 + l16] = bf16r(e[nt][r] * sc);
    }
    __syncthreads();

    // coalesced uint4 stores: 64 rows x 16 uint4
    for (int c = threadIdx.x; c < 64 * 16; c += 256) {
        int r = c >> 4, cu = c & 15;
        int g = row0 + r;
        if (g < nrows) {
            uint4 vv = *(const uint4*)&Wl[r * 136 + cu * 8];
            *(uint4*)&y[(size_t)g * 128 + cu * 8] = vv;
        }
    }
}

// ---------------------------------------------------------------------------
// Fused heads: out = [mu | logsig2], X = concat(h, nodes) [rows x 256 k].
// Round-12: fix r11's two measured regressions. (a) 66KB LDS -> 2 blocks/CU,
// occupancy 17%: B (wht) now staged in TWO 32KB K-halves (stage half, 32
// MFMAs, barrier, restage) -> ~5 blocks/CU. (b) 1.6M bank conflicts: pad-264
// is in the "pad doesn't fix row-major D=128" family (guide G4/m214); use
// the verified XOR swizzle: stride 128 shorts (256B), 16B-chunk index
// c ^ (r&7) on both staging write and ds_read_b128 -> every bank at the
// 8-access minimum. A stays direct-from-global (validated r8/r9).
// ---------------------------------------------------------------------------
__global__ __launch_bounds__(256)
void head_mfma(const unsigned short* __restrict__ h, const float* __restrict__ nodes,
               const unsigned short* __restrict__ Wt,
               const float* __restrict__ bmu, const float* __restrict__ bls,
               float* __restrict__ out, int nrows) {
    __shared__ unsigned short Wl[128 * 128];   // 32KB K-half B tile, XOR-swizzled
    const int row0 = blockIdx.x * 64;

    const int lane = threadIdx.x & 63;
    const int w = threadIdx.x >> 6;      // wave owns rows w*16 .. w*16+15
    const int q = lane >> 4;
    const int l16 = lane & 15;
    const int grow = row0 + w * 16 + l16;
    const bool rv = (grow < nrows);

    // A fragments direct from global: 8 K-slices of 32 (h cols 0..127, nodes 128..255)
    short8 af[8];
    #pragma unroll
    for (int k0 = 0; k0 < 4; ++k0) {
        short8 z = {0, 0, 0, 0, 0, 0, 0, 0};
        if (rv) z = *(const short8*)&h[(size_t)grow * 128 + k0 * 32 + q * 8];
        af[k0] = z;
    }
    #pragma unroll
    for (int k0 = 0; k0 < 4; ++k0) {
        float4 a = make_float4(0.f, 0.f, 0.f, 0.f);
        float4 b = make_float4(0.f, 0.f, 0.f, 0.f);
        if (rv) {
            a = *(const float4*)&nodes[(size_t)grow * 128 + k0 * 32 + q * 8];
            b = *(const float4*)&nodes[(size_t)grow * 128 + k0 * 32 + q * 8 + 4];
        }
        uint4 u = make_uint4(bf16pack2(a.x, a.y), bf16pack2(a.z, a.w),
                             bf16pack2(b.x, b.y), bf16pack2(b.z, b.w));
        af[4 + k0] = *(short8*)&u;
    }

    f32x4 acc[8] = {};                   // 8 output col-blocks of 16
    #pragma unroll
    for (int half = 0; half < 2; ++half) {
        if (half) __syncthreads();       // previous half's reads done
        // stage K-half of wht (128 n x 128 k = 32KB), XOR-swizzled chunks
        for (int i = threadIdx.x; i < 128 * 16; i += 256) {
            int r = i >> 4, c = i & 15;
            *(uint4*)&Wl[r * 128 + ((c ^ (r & 7)) * 8)] =
                *(const uint4*)&Wt[r * 256 + half * 128 + c * 8];
        }
        __syncthreads();
        #pragma unroll
        for (int nt = 0; nt < 8; ++nt) {
            const int row = nt * 16 + l16;
            #pragma unroll
            for (int kk = 0; kk < 4; ++kk) {
                short8 b = *(const short8*)&Wl[row * 128 + (((kk * 4 + q) ^ (row & 7)) * 8)];
                acc[nt] = __builtin_amdgcn_mfma_f32_16x16x32_bf16(af[half * 4 + kk], b, acc[nt], 0, 0, 0);
            }
        }
    }

    // bias per col-block: nt<4 -> mu cols nt*16+l16 ; nt>=4 -> ls cols
    float bv[8];
    #pragma unroll
    for (int nt = 0; nt < 4; ++nt) bv[nt] = bmu[nt * 16 + l16];
    #pragma unroll
    for (int nt = 4; nt < 8; ++nt) bv[nt] = bls[(nt - 4) * 16 + l16];

    float* const omu = out;
    float* const ols = out + (size_t)nrows * 64;
    #pragma unroll
    for (int r = 0; r < 4; ++r) {
        const int g = row0 + w * 16 + q * 4 + r;
        if (g < nrows) {
            #pragma unroll
            for (int nt = 0; nt < 4; ++nt)
                omu[(size_t)g * 64 + nt * 16 + l16] = acc[nt][r] + bv[nt];
            #pragma unroll
            for (int nt = 4; nt < 8; ++nt)
                ols[(size_t)g * 64 + (nt - 4) * 16 + l16] = acc[nt][r] + bv[nt];
        }
    }
}

extern "C" void kernel_launch(void* const* d_in, const int* in_sizes, int n_in,
                              void* d_out, int out_size, void* d_ws, size_t ws_size,
                              hipStream_t stream) {
    const float* nodes     = (const float*)d_in[0];
    const int*   senders   = (const int*)d_in[1];
    const int*   receivers = (const int*)d_in[2];
    const float* W0  = (const float*)d_in[3];
    const float* b0  = (const float*)d_in[4];
    const float* W1  = (const float*)d_in[5];
    const float* b1  = (const float*)d_in[6];
    const float* Wmu = (const float*)d_in[7];
    const float* bmu = (const float*)d_in[8];
    const float* Wls = (const float*)d_in[9];
    const float* bls = (const float*)d_in[10];
    float* out = (float*)d_out;

    const int N = N_NODES;
    const int NT64 = (N + 63) / 64;      // 64-row tiles

    // ws: inv_s[N] f32 | inv_r[N] f32 | buf0[N*128] bf16 | buf1[N*128] bf16 | weights
    float* inv_s = (float*)d_ws;
    float* inv_r = inv_s + N;
    unsigned short* buf0 = (unsigned short*)(inv_r + N);
    unsigned short* buf1 = buf0 + (size_t)N * 128;
    unsigned short* w0t  = buf1 + (size_t)N * 128;
    unsigned short* w1t  = w0t + 128 * 128;
    unsigned short* wht  = w1t + 128 * 128;

    // sort metadata in d_out (scratch until heads write it): offs[N+1] | srt[E]
    int* offs = (int*)d_out;
    int* srt  = offs + (N + 1);

    // setup-only temps alias buf0 (dead before layer-1 writes buf0):
    // pairs[E] uint2 | sbuf[E] | hR[NCHUNK*BROWS] | hS | baseR[512] | baseS[512]
    uint2* pairs = (uint2*)buf0;
    int* sbuf  = (int*)(pairs + N_EDGES);
    int* hR    = sbuf + N_EDGES;
    int* hS    = hR + NCHUNK * BROWS;
    int* baseR = hS + NCHUNK * BROWS;
    int* baseS = baseR + 512;

    // --- weight prep (bf16 transposed, one launch) ---
    prep_weights<<<256, 256, 0, stream>>>(W0, W1, Wmu, Wls, w0t, w1t, wht);

    // --- counting sort of edges by receiver + degrees (all atomics in LDS) ---
    bucket_hist<<<NCHUNK, 1024, 0, stream>>>(receivers, senders, hR, hS);
    bucket_scan<<<1, 512, 0, stream>>>(hR, hS, baseR, baseS);
    bucket_scatter<<<NCHUNK, 1024, 0, stream>>>(receivers, senders, hR, hS, pairs, sbuf);
    bucket_finalize<<<NBUCK, 256, 0, stream>>>(pairs, baseR, offs, srt, inv_r, N);
    sender_count<<<NBUCK, 256, 0, stream>>>(sbuf, baseS, inv_s, N);

    // --- layer 1 ---
    gc_mfma<false><<<NT64, 256, 0, stream>>>(nodes, w0t, b0, inv_s, buf0, N);
    aggregate_kernel<<<2048, 256, 0, stream>>>((const uint4*)buf0, (uint4*)buf1,
                                               offs, srt, inv_r, N);

    // --- layer 2 (input pre-scaled bf16) ---
    gc_mfma<true><<<NT64, 256, 0, stream>>>(buf1, w1t, b1, inv_s, buf0, N);
    aggregate_kernel<<<2048, 256, 0, stream>>>((const uint4*)buf0, (uint4*)buf1,
                                               offs, srt, inv_r, N);

    // --- fused heads: out = [mu | logsig2] ---
    head_mfma<<<NT64, 256, 0, stream>>>(buf1, nodes, wht, bmu, bls, out, N);
}

// Round 13
// 268.432 us; speedup vs baseline: 1.0681x; 1.0076x over previous
//
#include <hip/hip_runtime.h>

#define N_NODES 100000
#define N_EDGES 600000

#define NBUCK 391                 // ceil(N_NODES/256) receiver/sender buckets
#define BROWS 512                 // padded bucket-row stride
#define NCHUNK 128                // blocks for hist/scatter passes
#define V4_TOTAL (N_EDGES / 4)    // 150000 int4
#define V4_CHUNK ((V4_TOTAL + NCHUNK - 1) / NCHUNK)

typedef __attribute__((ext_vector_type(8))) short short8;   // 8 bf16 (4 VGPRs)
typedef __attribute__((ext_vector_type(4))) float f32x4;    // MFMA accumulator

// round-to-nearest-even f32 -> bf16
__device__ inline unsigned short bf16r(float x) {
    unsigned u = __float_as_uint(x);
    return (unsigned short)((u + 0x7FFFu + ((u >> 16) & 1u)) >> 16);
}
__device__ inline unsigned bf16pack2(float x, float y) {
    unsigned ux = __float_as_uint(x), uy = __float_as_uint(y);
    ux = (ux + 0x7FFFu + ((ux >> 16) & 1u)) >> 16;
    uy = (uy + 0x7FFFu + ((uy >> 16) & 1u)) >> 16;
    return ux | (uy << 16);
}

// ---------------------------------------------------------------------------
// Fused weight prep: w0t/w1t = transposed bf16 of W0/W1 (128x128);
// wht[n][k], n<64 from Wmu, n>=64 from Wls (128 n x 256 k).
// ---------------------------------------------------------------------------
__global__ void prep_weights(const float* __restrict__ W0, const float* __restrict__ W1,
                             const float* __restrict__ Wmu, const float* __restrict__ Wls,
                             unsigned short* __restrict__ w0t, unsigned short* __restrict__ w1t,
                             unsigned short* __restrict__ wht) {
    int i = blockIdx.x * 256 + threadIdx.x;   // 0 .. 65535
    if (i < 16384) {
        int nn = i >> 7, k = i & 127;
        w0t[i] = bf16r(W0[k * 128 + nn]);
    } else if (i < 32768) {
        int j = i - 16384;
        int nn = j >> 7, k = j & 127;
        w1t[j] = bf16r(W1[k * 128 + nn]);
    } else {
        int j = i - 32768;
        int nn = j >> 8, k = j & 255;
        float v = (nn < 64) ? Wmu[k * 64 + nn] : Wls[k * 64 + (nn - 64)];
        wht[j] = bf16r(v);
    }
}

// ---------------------------------------------------------------------------
// 2-pass bucket counting sort, ALL atomics in LDS (r1-r4 evidence: memory-side
// fabric atomics ~60us floor; scope tricks don't help; redundant streaming
// worse). Every edge read O(1) times; coarse buckets (id>>8) fit LDS.
// ---------------------------------------------------------------------------
__global__ __launch_bounds__(1024)
void bucket_hist(const int* __restrict__ receivers, const int* __restrict__ senders,
                 int* __restrict__ hR, int* __restrict__ hS) {
    __shared__ int cR[BROWS], cS[BROWS];
    const int t = threadIdx.x;
    if (t < BROWS) { cR[t] = 0; cS[t] = 0; }
    __syncthreads();
    const int v0 = blockIdx.x * V4_CHUNK;
    const int v1 = min(v0 + V4_CHUNK, V4_TOTAL);
    for (int i = v0 + t; i < v1; i += 1024) {
        const int4 r = ((const int4*)receivers)[i];
        const int4 s = ((const int4*)senders)[i];
        atomicAdd(&cR[r.x >> 8], 1); atomicAdd(&cR[r.y >> 8], 1);
        atomicAdd(&cR[r.z >> 8], 1); atomicAdd(&cR[r.w >> 8], 1);
        atomicAdd(&cS[s.x >> 8], 1); atomicAdd(&cS[s.y >> 8], 1);
        atomicAdd(&cS[s.z >> 8], 1); atomicAdd(&cS[s.w >> 8], 1);
    }
    __syncthreads();
    if (t < BROWS) {
        hR[blockIdx.x * BROWS + t] = cR[t];
        hS[blockIdx.x * BROWS + t] = cS[t];
    }
}

// single block: bucket totals -> exclusive bucket bases; convert h matrices
// in place to global scatter cursors (base + per-block prefix within bucket)
__global__ __launch_bounds__(512)
void bucket_scan(int* __restrict__ hR, int* __restrict__ hS,
                 int* __restrict__ baseR, int* __restrict__ baseS) {
    __shared__ int a[BROWS], b[BROWS], a2[BROWS], b2[BROWS];
    const int t = threadIdx.x;
    int totR = 0, totS = 0;
    for (int blk = 0; blk < NCHUNK; ++blk) {
        totR += hR[blk * BROWS + t];
        totS += hS[blk * BROWS + t];
    }
    a[t] = totR; a2[t] = totS;
    __syncthreads();
    int* pin = a; int* pout = b; int* qin = a2; int* qout = b2;
    for (int off = 1; off < BROWS; off <<= 1) {
        pout[t] = pin[t] + ((t >= off) ? pin[t - off] : 0);
        qout[t] = qin[t] + ((t >= off) ? qin[t - off] : 0);
        __syncthreads();
        int* tmp = pin; pin = pout; pout = tmp;
        tmp = qin; qin = qout; qout = tmp;
    }
    const int bR = pin[t] - totR;     // exclusive
    const int bS = qin[t] - totS;
    if (t <= NBUCK) { baseR[t] = (t == NBUCK) ? N_EDGES : bR; }
    if (t <= NBUCK) { baseS[t] = (t == NBUCK) ? N_EDGES : bS; }
    int curR = bR, curS = bS;
    for (int blk = 0; blk < NCHUNK; ++blk) {
        const int vR = hR[blk * BROWS + t]; hR[blk * BROWS + t] = curR; curR += vR;
        const int vS = hS[blk * BROWS + t]; hS[blk * BROWS + t] = curS; curS += vS;
    }
}

__global__ __launch_bounds__(1024)
void bucket_scatter(const int* __restrict__ receivers, const int* __restrict__ senders,
                    const int* __restrict__ hR, const int* __restrict__ hS,
                    uint2* __restrict__ pairs, int* __restrict__ sbuf) {
    __shared__ int cR[BROWS], cS[BROWS];
    const int t = threadIdx.x;
    if (t < BROWS) {
        cR[t] = hR[blockIdx.x * BROWS + t];
        cS[t] = hS[blockIdx.x * BROWS + t];
    }
    __syncthreads();
    const int v0 = blockIdx.x * V4_CHUNK;
    const int v1 = min(v0 + V4_CHUNK, V4_TOTAL);
    for (int i = v0 + t; i < v1; i += 1024) {
        const int4 r = ((const int4*)receivers)[i];
        const int4 s = ((const int4*)senders)[i];
        int p;
        p = atomicAdd(&cR[r.x >> 8], 1); pairs[p] = make_uint2((unsigned)r.x, (unsigned)s.x);
        p = atomicAdd(&cR[r.y >> 8], 1); pairs[p] = make_uint2((unsigned)r.y, (unsigned)s.y);
        p = atomicAdd(&cR[r.z >> 8], 1); pairs[p] = make_uint2((unsigned)r.z, (unsigned)s.z);
        p = atomicAdd(&cR[r.w >> 8], 1); pairs[p] = make_uint2((unsigned)r.w, (unsigned)s.w);
        p = atomicAdd(&cS[s.x >> 8], 1); sbuf[p] = s.x;
        p = atomicAdd(&cS[s.y >> 8], 1); sbuf[p] = s.y;
        p = atomicAdd(&cS[s.z >> 8], 1); sbuf[p] = s.z;
        p = atomicAdd(&cS[s.w >> 8], 1); sbuf[p] = s.w;
    }
}

// ---------------------------------------------------------------------------
// Merged finalize: blocks [0,NBUCK) = receiver buckets (LDS count -> scan ->
// offs/inv_r -> cursor scatter into srt); blocks [NBUCK,2*NBUCK) = sender
// buckets (LDS count -> inv_s). One launch instead of two.
// ---------------------------------------------------------------------------
__global__ __launch_bounds__(256)
void bucket_final2(const uint2* __restrict__ pairs, const int* __restrict__ sbuf,
                   const int* __restrict__ baseR, const int* __restrict__ baseS,
                   int* __restrict__ offs, int* __restrict__ srt,
                   float* __restrict__ inv_r, float* __restrict__ inv_s, int n) {
    __shared__ int cnt[256], cur[256];
    __shared__ int sa[256], sb[256];
    const int t = threadIdx.x;
    if ((int)blockIdx.x >= NBUCK) {
        // ---- sender-degree path ----
        const int b = (int)blockIdx.x - NBUCK;
        const int e0 = baseS[b], e1 = baseS[b + 1];
        cnt[t] = 0;
        __syncthreads();
        for (int i = e0 + t; i < e1; i += 256)
            atomicAdd(&cnt[sbuf[i] & 255], 1);
        __syncthreads();
        const int node = (b << 8) + t;
        if (node < n) inv_s[node] = rsqrtf(fmaxf((float)cnt[t], 1.0f));
        return;
    }
    // ---- receiver path ----
    const int b = blockIdx.x;
    const int e0 = baseR[b], e1 = baseR[b + 1];
    cnt[t] = 0;
    __syncthreads();
    for (int i = e0 + t; i < e1; i += 256)
        atomicAdd(&cnt[pairs[i].x & 255u], 1);
    __syncthreads();
    const int v = cnt[t];
    sa[t] = v;
    __syncthreads();
    int* pin = sa; int* pout = sb;
    for (int off = 1; off < 256; off <<= 1) {
        pout[t] = pin[t] + ((t >= off) ? pin[t - off] : 0);
        __syncthreads();
        int* tmp = pin; pin = pout; pout = tmp;
    }
    cur[t] = pin[t] - v;              // exclusive local offset (= running cursor)
    const int node = (b << 8) + t;
    if (node < n) {
        offs[node] = e0 + pin[t] - v;
        inv_r[node] = rsqrtf(fmaxf((float)v, 1.0f));
    }
    if (b == 0 && t == 0) offs[n] = N_EDGES;
    __syncthreads();
    for (int i = e0 + t; i < e1; i += 256) {
        const uint2 pr = pairs[i];
        const int p = atomicAdd(&cur[pr.x & 255u], 1);
        srt[e0 + p] = (int)pr.y;
    }
}

// ---------------------------------------------------------------------------
// dst[r] = bf16( scale[r] * sum over incoming edges of src[sender] )
// Round-13: 16 gathers in flight per lane (was 8) -> 256B/lane outstanding.
// Falsifiable test of "aggregate still latency-bound": if null, it's at the
// L3 random-gather ceiling and the next lever is byte-reduction/fusion.
// Degree ~Poisson(6): one 16-chunk covers nearly all receivers; masked
// loads are exec-masked (no memory traffic).
// ---------------------------------------------------------------------------
__global__ __launch_bounds__(256)
void aggregate_kernel(const uint4* __restrict__ src, uint4* __restrict__ dst,
                      const int* __restrict__ offs, const int* __restrict__ srt,
                      const float* __restrict__ scale, int n) {
    const int lane = threadIdx.x & 63;
    const int wave = threadIdx.x >> 6;
    const int grp  = lane >> 4;          // 0..3 (receiver group within wave)
    const int l16  = lane & 15;
    const int wid  = blockIdx.x * 4 + wave;      // wave index
    const int nwv  = gridDim.x * 4;              // total waves
    const unsigned grpbase = lane & 48;          // grp*16, for shfl source

    for (int rb = wid * 4; rb < n; rb += nwv * 4) {   // wave-uniform
        const int r = rb + grp;
        const bool valid = (r < n);
        int beg = 0, deg = 0;
        if (valid) { beg = offs[r]; deg = offs[r + 1] - beg; }
        float ax[8];
        #pragma unroll
        for (int k = 0; k < 8; ++k) ax[k] = 0.0f;

        for (int j0 = 0; ; j0 += 16) {
            const int rem = deg - j0;            // group-uniform
            int wm = rem;                        // wave max remaining
            wm = max(wm, __shfl_xor(wm, 16));
            wm = max(wm, __shfl_xor(wm, 32));
            if (wm <= 0) break;
            const int idx = (j0 + l16 < deg) ? srt[beg + j0 + l16] : 0;
            uint4 v[16];
            #pragma unroll
            for (int k = 0; k < 16; ++k) {
                const int s = __shfl(idx, grpbase + k);
                v[k] = make_uint4(0u, 0u, 0u, 0u);
                if (k < rem) v[k] = src[(size_t)s * 16 + l16];
            }
            #pragma unroll
            for (int k = 0; k < 16; ++k) {
                ax[0] += __uint_as_float(v[k].x << 16);
                ax[1] += __uint_as_float(v[k].x & 0xFFFF0000u);
                ax[2] += __uint_as_float(v[k].y << 16);
                ax[3] += __uint_as_float(v[k].y & 0xFFFF0000u);
                ax[4] += __uint_as_float(v[k].z << 16);
                ax[5] += __uint_as_float(v[k].z & 0xFFFF0000u);
                ax[6] += __uint_as_float(v[k].w << 16);
                ax[7] += __uint_as_float(v[k].w & 0xFFFF0000u);
            }
        }
        if (valid) {
            const float sc = scale[r];
            uint4 o;
            o.x = bf16pack2(ax[0] * sc, ax[1] * sc);
            o.y = bf16pack2(ax[2] * sc, ax[3] * sc);
            o.z = bf16pack2(ax[4] * sc, ax[5] * sc);
            o.w = bf16pack2(ax[6] * sc, ax[7] * sc);
            dst[(size_t)r * 16 + l16] = o;
        }
    }
}

// ---------------------------------------------------------------------------
// MFMA graph-conv layer: y = bf16( softmax(relu(x @ W + b)) * inv_out )
// r9 structure (validated: 41.5 -> ~20us): A direct-from-global into fragment
// registers; B (Wt) staged once per block in LDS (padded stride 136);
// wave-local softmax, no max-subtract; Wl reused for coalesced output stage.
// ---------------------------------------------------------------------------
template<bool IN_BF16>
__global__ __launch_bounds__(256)
void gc_mfma(const void* __restrict__ xv, const unsigned short* __restrict__ Wt,
             const float* __restrict__ bias, const float* __restrict__ inv_out,
             unsigned short* __restrict__ y, int nrows) {
    __shared__ unsigned short Wl[128 * 136];   // B tile; later reused for output
    __shared__ float sinv[64];
    const int row0 = blockIdx.x * 64;

    const int lane = threadIdx.x & 63;
    const int w = threadIdx.x >> 6;      // wave owns rows w*16 .. w*16+15
    const int q = lane >> 4;
    const int l16 = lane & 15;
    const int grow = row0 + w * 16 + l16;   // row this lane loads A from
    const bool rv = (grow < nrows);

    // A fragments direct from global (no LDS) - issue before staging barrier
    short8 af[4];
    if (IN_BF16) {
        const unsigned short* x = (const unsigned short*)xv;
        #pragma unroll
        for (int k0 = 0; k0 < 4; ++k0) {
            short8 z = {0, 0, 0, 0, 0, 0, 0, 0};
            if (rv) z = *(const short8*)&x[(size_t)grow * 128 + k0 * 32 + q * 8];
            af[k0] = z;
        }
    } else {
        const float* x = (const float*)xv;
        #pragma unroll
        for (int k0 = 0; k0 < 4; ++k0) {
            float4 a = make_float4(0.f, 0.f, 0.f, 0.f);
            float4 b = make_float4(0.f, 0.f, 0.f, 0.f);
            if (rv) {
                a = *(const float4*)&x[(size_t)grow * 128 + k0 * 32 + q * 8];
                b = *(const float4*)&x[(size_t)grow * 128 + k0 * 32 + q * 8 + 4];
            }
            uint4 u = make_uint4(bf16pack2(a.x, a.y), bf16pack2(a.z, a.w),
                                 bf16pack2(b.x, b.y), bf16pack2(b.z, b.w));
            af[k0] = *(short8*)&u;
        }
    }

    if (threadIdx.x < 64) {
        int g = row0 + threadIdx.x;
        sinv[threadIdx.x] = (g < nrows) ? inv_out[g] : 1.0f;
    }

    // stage Wt (128 x 128 bf16) into LDS, padded row stride 136
    for (int i = threadIdx.x; i < 128 * 16; i += 256) {
        int r = i >> 4, c = i & 15;
        *(uint4*)&Wl[r * 136 + c * 8] = *(const uint4*)&Wt[r * 128 + c * 8];
    }
    __syncthreads();

    f32x4 acc[8] = {};                   // 8 col-blocks of 16
    #pragma unroll
    for (int nt = 0; nt < 8; ++nt) {
        #pragma unroll
        for (int k0 = 0; k0 < 4; ++k0) {
            short8 b = *(const short8*)&Wl[(nt * 16 + l16) * 136 + k0 * 32 + q * 8];
            acc[nt] = __builtin_amdgcn_mfma_f32_16x16x32_bf16(af[k0], b, acc[nt], 0, 0, 0);
        }
    }

    // bias -> relu -> exp (no max-subtract: relu-bounded) -> wave-local row sum
    float e[8][4];
    float s[4] = {0.f, 0.f, 0.f, 0.f};
    #pragma unroll
    for (int nt = 0; nt < 8; ++nt) {
        const float bv = bias[nt * 16 + l16];
        #pragma unroll
        for (int r = 0; r < 4; ++r) {
            float ev = __expf(fmaxf(acc[nt][r] + bv, 0.0f));
            e[nt][r] = ev;
            s[r] += ev;
        }
    }
    #pragma unroll
    for (int off = 1; off < 16; off <<= 1)
        #pragma unroll
        for (int r = 0; r < 4; ++r)
            s[r] += __shfl_xor(s[r], off);

    __syncthreads();                     // all B reads done; Wl reusable

    // scale and stage bf16 output (rows w*16+q*4+r) into Wl
    #pragma unroll
    for (int r = 0; r < 4; ++r) {
        const int rl = w * 16 + q * 4 + r;
        const float sc = sinv[rl] / s[r];
        #pragma unroll
        for (int nt = 0; nt < 8; ++nt)
            Wl[rl * 136 + nt * 16 + l16] = bf16r(e[nt][r] * sc);
    }
    __syncthreads();

    // coalesced uint4 stores: 64 rows x 16 uint4
    for (int c = threadIdx.x; c < 64 * 16; c += 256) {
        int r = c >> 4, cu = c & 15;
        int g = row0 + r;
        if (g < nrows) {
            uint4 vv = *(const uint4*)&Wl[r * 136 + cu * 8];
            *(uint4*)&y[(size_t)g * 128 + cu * 8] = vv;
        }
    }
}

// ---------------------------------------------------------------------------
// Fused heads: out = [mu | logsig2], X = concat(h, nodes) [rows x 256 k].
// r12 structure (validated: 50.3 -> out of top-5): A direct-from-global;
// B staged in TWO 32KB XOR-swizzled K-halves (occupancy + conflict fix).
// ---------------------------------------------------------------------------
__global__ __launch_bounds__(256)
void head_mfma(const unsigned short* __restrict__ h, const float* __restrict__ nodes,
               const unsigned short* __restrict__ Wt,
               const float* __restrict__ bmu, const float* __restrict__ bls,
               float* __restrict__ out, int nrows) {
    __shared__ unsigned short Wl[128 * 128];   // 32KB K-half B tile, XOR-swizzled
    const int row0 = blockIdx.x * 64;

    const int lane = threadIdx.x & 63;
    const int w = threadIdx.x >> 6;      // wave owns rows w*16 .. w*16+15
    const int q = lane >> 4;
    const int l16 = lane & 15;
    const int grow = row0 + w * 16 + l16;
    const bool rv = (grow < nrows);

    // A fragments direct from global: 8 K-slices of 32 (h cols 0..127, nodes 128..255)
    short8 af[8];
    #pragma unroll
    for (int k0 = 0; k0 < 4; ++k0) {
        short8 z = {0, 0, 0, 0, 0, 0, 0, 0};
        if (rv) z = *(const short8*)&h[(size_t)grow * 128 + k0 * 32 + q * 8];
        af[k0] = z;
    }
    #pragma unroll
    for (int k0 = 0; k0 < 4; ++k0) {
        float4 a = make_float4(0.f, 0.f, 0.f, 0.f);
        float4 b = make_float4(0.f, 0.f, 0.f, 0.f);
        if (rv) {
            a = *(const float4*)&nodes[(size_t)grow * 128 + k0 * 32 + q * 8];
            b = *(const float4*)&nodes[(size_t)grow * 128 + k0 * 32 + q * 8 + 4];
        }
        uint4 u = make_uint4(bf16pack2(a.x, a.y), bf16pack2(a.z, a.w),
                             bf16pack2(b.x, b.y), bf16pack2(b.z, b.w));
        af[4 + k0] = *(short8*)&u;
    }

    f32x4 acc[8] = {};                   // 8 output col-blocks of 16
    #pragma unroll
    for (int half = 0; half < 2; ++half) {
        if (half) __syncthreads();       // previous half's reads done
        // stage K-half of wht (128 n x 128 k = 32KB), XOR-swizzled chunks
        for (int i = threadIdx.x; i < 128 * 16; i += 256) {
            int r = i >> 4, c = i & 15;
            *(uint4*)&Wl[r * 128 + ((c ^ (r & 7)) * 8)] =
                *(const uint4*)&Wt[r * 256 + half * 128 + c * 8];
        }
        __syncthreads();
        #pragma unroll
        for (int nt = 0; nt < 8; ++nt) {
            const int row = nt * 16 + l16;
            #pragma unroll
            for (int kk = 0; kk < 4; ++kk) {
                short8 b = *(const short8*)&Wl[row * 128 + (((kk * 4 + q) ^ (row & 7)) * 8)];
                acc[nt] = __builtin_amdgcn_mfma_f32_16x16x32_bf16(af[half * 4 + kk], b, acc[nt], 0, 0, 0);
            }
        }
    }

    // bias per col-block: nt<4 -> mu cols nt*16+l16 ; nt>=4 -> ls cols
    float bv[8];
    #pragma unroll
    for (int nt = 0; nt < 4; ++nt) bv[nt] = bmu[nt * 16 + l16];
    #pragma unroll
    for (int nt = 4; nt < 8; ++nt) bv[nt] = bls[(nt - 4) * 16 + l16];

    float* const omu = out;
    float* const ols = out + (size_t)nrows * 64;
    #pragma unroll
    for (int r = 0; r < 4; ++r) {
        const int g = row0 + w * 16 + q * 4 + r;
        if (g < nrows) {
            #pragma unroll
            for (int nt = 0; nt < 4; ++nt)
                omu[(size_t)g * 64 + nt * 16 + l16] = acc[nt][r] + bv[nt];
            #pragma unroll
            for (int nt = 4; nt < 8; ++nt)
                ols[(size_t)g * 64 + (nt - 4) * 16 + l16] = acc[nt][r] + bv[nt];
        }
    }
}

extern "C" void kernel_launch(void* const* d_in, const int* in_sizes, int n_in,
                              void* d_out, int out_size, void* d_ws, size_t ws_size,
                              hipStream_t stream) {
    const float* nodes     = (const float*)d_in[0];
    const int*   senders   = (const int*)d_in[1];
    const int*   receivers = (const int*)d_in[2];
    const float* W0  = (const float*)d_in[3];
    const float* b0  = (const float*)d_in[4];
    const float* W1  = (const float*)d_in[5];
    const float* b1  = (const float*)d_in[6];
    const float* Wmu = (const float*)d_in[7];
    const float* bmu = (const float*)d_in[8];
    const float* Wls = (const float*)d_in[9];
    const float* bls = (const float*)d_in[10];
    float* out = (float*)d_out;

    const int N = N_NODES;
    const int NT64 = (N + 63) / 64;      // 64-row tiles

    // ws: inv_s[N] f32 | inv_r[N] f32 | buf0[N*128] bf16 | buf1[N*128] bf16 | weights
    float* inv_s = (float*)d_ws;
    float* inv_r = inv_s + N;
    unsigned short* buf0 = (unsigned short*)(inv_r + N);
    unsigned short* buf1 = buf0 + (size_t)N * 128;
    unsigned short* w0t  = buf1 + (size_t)N * 128;
    unsigned short* w1t  = w0t + 128 * 128;
    unsigned short* wht  = w1t + 128 * 128;

    // sort metadata in d_out (scratch until heads write it): offs[N+1] | srt[E]
    int* offs = (int*)d_out;
    int* srt  = offs + (N + 1);

    // setup-only temps alias buf0 (dead before layer-1 writes buf0):
    // pairs[E] uint2 | sbuf[E] | hR[NCHUNK*BROWS] | hS | baseR[512] | baseS[512]
    uint2* pairs = (uint2*)buf0;
    int* sbuf  = (int*)(pairs + N_EDGES);
    int* hR    = sbuf + N_EDGES;
    int* hS    = hR + NCHUNK * BROWS;
    int* baseR = hS + NCHUNK * BROWS;
    int* baseS = baseR + 512;

    // --- weight prep (bf16 transposed, one launch) ---
    prep_weights<<<256, 256, 0, stream>>>(W0, W1, Wmu, Wls, w0t, w1t, wht);

    // --- counting sort of edges by receiver + degrees (all atomics in LDS) ---
    bucket_hist<<<NCHUNK, 1024, 0, stream>>>(receivers, senders, hR, hS);
    bucket_scan<<<1, 512, 0, stream>>>(hR, hS, baseR, baseS);
    bucket_scatter<<<NCHUNK, 1024, 0, stream>>>(receivers, senders, hR, hS, pairs, sbuf);
    bucket_final2<<<2 * NBUCK, 256, 0, stream>>>(pairs, sbuf, baseR, baseS,
                                                 offs, srt, inv_r, inv_s, N);

    // --- layer 1 ---
    gc_mfma<false><<<NT64, 256, 0, stream>>>(nodes, w0t, b0, inv_s, buf0, N);
    aggregate_kernel<<<2048, 256, 0, stream>>>((const uint4*)buf0, (uint4*)buf1,
                                               offs, srt, inv_r, N);

    // --- layer 2 (input pre-scaled bf16) ---
    gc_mfma<true><<<NT64, 256, 0, stream>>>(buf1, w1t, b1, inv_s, buf0, N);
    aggregate_kernel<<<2048, 256, 0, stream>>>((const uint4*)buf0, (uint4*)buf1,
                                               offs, srt, inv_r, N);

    // --- fused heads: out = [mu | logsig2] ---
    head_mfma<<<NT64, 256, 0, stream>>>(buf1, nodes, wht, bmu, bls, out, N);
}

// Round 14
// 247.525 us; speedup vs baseline: 1.1583x; 1.0845x over previous
//
#include <hip/hip_runtime.h>

#define N_NODES 100000
#define N_EDGES 600000

#define NBUCK 391                 // ceil(N_NODES/256) receiver/sender buckets
#define BROWS 512                 // padded bucket-row stride (LDS arrays)
#define BCAP  2048                // fixed per-bucket region capacity (13-sigma)
#define NCHUNK 128                // blocks for the scatter pass
#define V4_TOTAL (N_EDGES / 4)    // 150000 int4
#define V4_CHUNK ((V4_TOTAL + NCHUNK - 1) / NCHUNK)

typedef __attribute__((ext_vector_type(8))) short short8;   // 8 bf16 (4 VGPRs)
typedef __attribute__((ext_vector_type(4))) float f32x4;    // MFMA accumulator

// round-to-nearest-even f32 -> bf16
__device__ inline unsigned short bf16r(float x) {
    unsigned u = __float_as_uint(x);
    return (unsigned short)((u + 0x7FFFu + ((u >> 16) & 1u)) >> 16);
}
__device__ inline unsigned bf16pack2(float x, float y) {
    unsigned ux = __float_as_uint(x), uy = __float_as_uint(y);
    ux = (ux + 0x7FFFu + ((ux >> 16) & 1u)) >> 16;
    uy = (uy + 0x7FFFu + ((uy >> 16) & 1u)) >> 16;
    return ux | (uy << 16);
}

// ---------------------------------------------------------------------------
// Single-pass reservation sort (replaces hist+scan+scatter; r13 evidence:
// ~80us of the total is sort-chain + launch gaps). Each block LDS-counts its
// chunk, reserves a range in each bucket's fixed-capacity region via ONE
// global atomicAdd per (block,bucket) (131k fabric atomics ~3us, vs 1.2M
// per-edge ones ~60us), then LDS-cursor scatters. Buckets are gapped: node
// degree comes from an explicit deg[] array, not offs[r+1]-offs[r].
// Blocks [NCHUNK, NCHUNK+64): prep_weights path (merged, saves a launch).
// ---------------------------------------------------------------------------
__global__ __launch_bounds__(1024)
void res_scatter(const int* __restrict__ receivers, const int* __restrict__ senders,
                 const float* __restrict__ W0, const float* __restrict__ W1,
                 const float* __restrict__ Wmu, const float* __restrict__ Wls,
                 unsigned short* __restrict__ w0t, unsigned short* __restrict__ w1t,
                 unsigned short* __restrict__ wht,
                 int* __restrict__ gcurR, int* __restrict__ gcurS,
                 uint2* __restrict__ pairs, int* __restrict__ sbuf) {
    const int t = threadIdx.x;
    if ((int)blockIdx.x >= NCHUNK) {
        // ---- fused weight prep: 64 blocks x 1024 threads = 65536 elems ----
        int i = ((int)blockIdx.x - NCHUNK) * 1024 + t;
        if (i < 16384) {
            int nn = i >> 7, k = i & 127;
            w0t[i] = bf16r(W0[k * 128 + nn]);
        } else if (i < 32768) {
            int j = i - 16384;
            int nn = j >> 7, k = j & 127;
            w1t[j] = bf16r(W1[k * 128 + nn]);
        } else {
            int j = i - 32768;
            int nn = j >> 8, k = j & 255;
            float v = (nn < 64) ? Wmu[k * 64 + nn] : Wls[k * 64 + (nn - 64)];
            wht[j] = bf16r(v);
        }
        return;
    }
    __shared__ int cR[BROWS], cS[BROWS];
    if (t < BROWS) { cR[t] = 0; cS[t] = 0; }
    __syncthreads();
    const int v0 = blockIdx.x * V4_CHUNK;
    const int v1 = min(v0 + V4_CHUNK, V4_TOTAL);
    // pass 1: count chunk's edges per bucket (LDS atomics)
    for (int i = v0 + t; i < v1; i += 1024) {
        const int4 r = ((const int4*)receivers)[i];
        const int4 s = ((const int4*)senders)[i];
        atomicAdd(&cR[r.x >> 8], 1); atomicAdd(&cR[r.y >> 8], 1);
        atomicAdd(&cR[r.z >> 8], 1); atomicAdd(&cR[r.w >> 8], 1);
        atomicAdd(&cS[s.x >> 8], 1); atomicAdd(&cS[s.y >> 8], 1);
        atomicAdd(&cS[s.z >> 8], 1); atomicAdd(&cS[s.w >> 8], 1);
    }
    __syncthreads();
    // reserve [base, base+count) in each bucket's region; turn cR/cS into cursors
    if (t < BROWS) {
        int c = cR[t];
        cR[t] = t * BCAP + (c ? atomicAdd(&gcurR[t], c) : 0);
        c = cS[t];
        cS[t] = t * BCAP + (c ? atomicAdd(&gcurS[t], c) : 0);
    }
    __syncthreads();
    // pass 2: scatter via LDS cursors
    for (int i = v0 + t; i < v1; i += 1024) {
        const int4 r = ((const int4*)receivers)[i];
        const int4 s = ((const int4*)senders)[i];
        int p;
        p = atomicAdd(&cR[r.x >> 8], 1); pairs[p] = make_uint2((unsigned)r.x, (unsigned)s.x);
        p = atomicAdd(&cR[r.y >> 8], 1); pairs[p] = make_uint2((unsigned)r.y, (unsigned)s.y);
        p = atomicAdd(&cR[r.z >> 8], 1); pairs[p] = make_uint2((unsigned)r.z, (unsigned)s.z);
        p = atomicAdd(&cR[r.w >> 8], 1); pairs[p] = make_uint2((unsigned)r.w, (unsigned)s.w);
        p = atomicAdd(&cS[s.x >> 8], 1); sbuf[p] = s.x;
        p = atomicAdd(&cS[s.y >> 8], 1); sbuf[p] = s.y;
        p = atomicAdd(&cS[s.z >> 8], 1); sbuf[p] = s.z;
        p = atomicAdd(&cS[s.w >> 8], 1); sbuf[p] = s.w;
    }
}

// ---------------------------------------------------------------------------
// Merged finalize: blocks [0,NBUCK) = receiver buckets (LDS count -> scan ->
// offs/deg/inv_r -> cursor scatter into srt); blocks [NBUCK,2*NBUCK) = sender
// buckets (LDS count -> inv_s). Bucket b occupies [b*BCAP, b*BCAP+fill).
// ---------------------------------------------------------------------------
__global__ __launch_bounds__(256)
void bucket_final2(const uint2* __restrict__ pairs, const int* __restrict__ sbuf,
                   const int* __restrict__ gcurR, const int* __restrict__ gcurS,
                   int* __restrict__ offs, int* __restrict__ deg_r,
                   int* __restrict__ srt,
                   float* __restrict__ inv_r, float* __restrict__ inv_s, int n) {
    __shared__ int cnt[256], cur[256];
    __shared__ int sa[256], sb[256];
    const int t = threadIdx.x;
    if ((int)blockIdx.x >= NBUCK) {
        // ---- sender-degree path ----
        const int b = (int)blockIdx.x - NBUCK;
        const int e0 = b * BCAP, e1 = b * BCAP + gcurS[b];
        cnt[t] = 0;
        __syncthreads();
        for (int i = e0 + t; i < e1; i += 256)
            atomicAdd(&cnt[sbuf[i] & 255], 1);
        __syncthreads();
        const int node = (b << 8) + t;
        if (node < n) inv_s[node] = rsqrtf(fmaxf((float)cnt[t], 1.0f));
        return;
    }
    // ---- receiver path ----
    const int b = blockIdx.x;
    const int e0 = b * BCAP, e1 = b * BCAP + gcurR[b];
    cnt[t] = 0;
    __syncthreads();
    for (int i = e0 + t; i < e1; i += 256)
        atomicAdd(&cnt[pairs[i].x & 255u], 1);
    __syncthreads();
    const int v = cnt[t];
    sa[t] = v;
    __syncthreads();
    int* pin = sa; int* pout = sb;
    for (int off = 1; off < 256; off <<= 1) {
        pout[t] = pin[t] + ((t >= off) ? pin[t - off] : 0);
        __syncthreads();
        int* tmp = pin; pin = pout; pout = tmp;
    }
    cur[t] = pin[t] - v;              // exclusive local offset (= running cursor)
    const int node = (b << 8) + t;
    if (node < n) {
        offs[node] = e0 + pin[t] - v;
        deg_r[node] = v;
        inv_r[node] = rsqrtf(fmaxf((float)v, 1.0f));
    }
    __syncthreads();
    for (int i = e0 + t; i < e1; i += 256) {
        const uint2 pr = pairs[i];
        const int p = atomicAdd(&cur[pr.x & 255u], 1);
        srt[e0 + p] = (int)pr.y;
    }
}

// ---------------------------------------------------------------------------
// dst[r] = bf16( scale[r] * sum over incoming edges of src[sender] )
// r13: at the L3 random-gather throughput ceiling (~4.2 TB/s; MLP16 vs MLP8
// was null). deg now from explicit array (gapped srt regions).
// ---------------------------------------------------------------------------
__global__ __launch_bounds__(256)
void aggregate_kernel(const uint4* __restrict__ src, uint4* __restrict__ dst,
                      const int* __restrict__ offs, const int* __restrict__ deg_r,
                      const int* __restrict__ srt,
                      const float* __restrict__ scale, int n) {
    const int lane = threadIdx.x & 63;
    const int wave = threadIdx.x >> 6;
    const int grp  = lane >> 4;          // 0..3 (receiver group within wave)
    const int l16  = lane & 15;
    const int wid  = blockIdx.x * 4 + wave;      // wave index
    const int nwv  = gridDim.x * 4;              // total waves
    const unsigned grpbase = lane & 48;          // grp*16, for shfl source

    for (int rb = wid * 4; rb < n; rb += nwv * 4) {   // wave-uniform
        const int r = rb + grp;
        const bool valid = (r < n);
        int beg = 0, deg = 0;
        if (valid) { beg = offs[r]; deg = deg_r[r]; }
        float ax[8];
        #pragma unroll
        for (int k = 0; k < 8; ++k) ax[k] = 0.0f;

        for (int j0 = 0; ; j0 += 16) {
            const int rem = deg - j0;            // group-uniform
            int wm = rem;                        // wave max remaining
            wm = max(wm, __shfl_xor(wm, 16));
            wm = max(wm, __shfl_xor(wm, 32));
            if (wm <= 0) break;
            const int idx = (j0 + l16 < deg) ? srt[beg + j0 + l16] : 0;
            uint4 v[16];
            #pragma unroll
            for (int k = 0; k < 16; ++k) {
                const int s = __shfl(idx, grpbase + k);
                v[k] = make_uint4(0u, 0u, 0u, 0u);
                if (k < rem) v[k] = src[(size_t)s * 16 + l16];
            }
            #pragma unroll
            for (int k = 0; k < 16; ++k) {
                ax[0] += __uint_as_float(v[k].x << 16);
                ax[1] += __uint_as_float(v[k].x & 0xFFFF0000u);
                ax[2] += __uint_as_float(v[k].y << 16);
                ax[3] += __uint_as_float(v[k].y & 0xFFFF0000u);
                ax[4] += __uint_as_float(v[k].z << 16);
                ax[5] += __uint_as_float(v[k].z & 0xFFFF0000u);
                ax[6] += __uint_as_float(v[k].w << 16);
                ax[7] += __uint_as_float(v[k].w & 0xFFFF0000u);
            }
        }
        if (valid) {
            const float sc = scale[r];
            uint4 o;
            o.x = bf16pack2(ax[0] * sc, ax[1] * sc);
            o.y = bf16pack2(ax[2] * sc, ax[3] * sc);
            o.z = bf16pack2(ax[4] * sc, ax[5] * sc);
            o.w = bf16pack2(ax[6] * sc, ax[7] * sc);
            dst[(size_t)r * 16 + l16] = o;
        }
    }
}

// ---------------------------------------------------------------------------
// MFMA graph-conv layer: y = bf16( softmax(relu(x @ W + b)) * inv_out )
// r9 structure (validated: 41.5 -> ~25us): A direct-from-global into fragment
// registers; B (Wt) staged once per block in LDS (padded stride 136);
// wave-local softmax, no max-subtract; Wl reused for coalesced output stage.
// ---------------------------------------------------------------------------
template<bool IN_BF16>
__global__ __launch_bounds__(256)
void gc_mfma(const void* __restrict__ xv, const unsigned short* __restrict__ Wt,
             const float* __restrict__ bias, const float* __restrict__ inv_out,
             unsigned short* __restrict__ y, int nrows) {
    __shared__ unsigned short Wl[128 * 136];   // B tile; later reused for output
    __shared__ float sinv[64];
    const int row0 = blockIdx.x * 64;

    const int lane = threadIdx.x & 63;
    const int w = threadIdx.x >> 6;      // wave owns rows w*16 .. w*16+15
    const int q = lane >> 4;
    const int l16 = lane & 15;
    const int grow = row0 + w * 16 + l16;   // row this lane loads A from
    const bool rv = (grow < nrows);

    // A fragments direct from global (no LDS) - issue before staging barrier
    short8 af[4];
    if (IN_BF16) {
        const unsigned short* x = (const unsigned short*)xv;
        #pragma unroll
        for (int k0 = 0; k0 < 4; ++k0) {
            short8 z = {0, 0, 0, 0, 0, 0, 0, 0};
            if (rv) z = *(const short8*)&x[(size_t)grow * 128 + k0 * 32 + q * 8];
            af[k0] = z;
        }
    } else {
        const float* x = (const float*)xv;
        #pragma unroll
        for (int k0 = 0; k0 < 4; ++k0) {
            float4 a = make_float4(0.f, 0.f, 0.f, 0.f);
            float4 b = make_float4(0.f, 0.f, 0.f, 0.f);
            if (rv) {
                a = *(const float4*)&x[(size_t)grow * 128 + k0 * 32 + q * 8];
                b = *(const float4*)&x[(size_t)grow * 128 + k0 * 32 + q * 8 + 4];
            }
            uint4 u = make_uint4(bf16pack2(a.x, a.y), bf16pack2(a.z, a.w),
                                 bf16pack2(b.x, b.y), bf16pack2(b.z, b.w));
            af[k0] = *(short8*)&u;
        }
    }

    if (threadIdx.x < 64) {
        int g = row0 + threadIdx.x;
        sinv[threadIdx.x] = (g < nrows) ? inv_out[g] : 1.0f;
    }

    // stage Wt (128 x 128 bf16) into LDS, padded row stride 136
    for (int i = threadIdx.x; i < 128 * 16; i += 256) {
        int r = i >> 4, c = i & 15;
        *(uint4*)&Wl[r * 136 + c * 8] = *(const uint4*)&Wt[r * 128 + c * 8];
    }
    __syncthreads();

    f32x4 acc[8] = {};                   // 8 col-blocks of 16
    #pragma unroll
    for (int nt = 0; nt < 8; ++nt) {
        #pragma unroll
        for (int k0 = 0; k0 < 4; ++k0) {
            short8 b = *(const short8*)&Wl[(nt * 16 + l16) * 136 + k0 * 32 + q * 8];
            acc[nt] = __builtin_amdgcn_mfma_f32_16x16x32_bf16(af[k0], b, acc[nt], 0, 0, 0);
        }
    }

    // bias -> relu -> exp (no max-subtract: relu-bounded) -> wave-local row sum
    float e[8][4];
    float s[4] = {0.f, 0.f, 0.f, 0.f};
    #pragma unroll
    for (int nt = 0; nt < 8; ++nt) {
        const float bv = bias[nt * 16 + l16];
        #pragma unroll
        for (int r = 0; r < 4; ++r) {
            float ev = __expf(fmaxf(acc[nt][r] + bv, 0.0f));
            e[nt][r] = ev;
            s[r] += ev;
        }
    }
    #pragma unroll
    for (int off = 1; off < 16; off <<= 1)
        #pragma unroll
        for (int r = 0; r < 4; ++r)
            s[r] += __shfl_xor(s[r], off);

    __syncthreads();                     // all B reads done; Wl reusable

    // scale and stage bf16 output (rows w*16+q*4+r) into Wl
    #pragma unroll
    for (int r = 0; r < 4; ++r) {
        const int rl = w * 16 + q * 4 + r;
        const float sc = sinv[rl] / s[r];
        #pragma unroll
        for (int nt = 0; nt < 8; ++nt)
            Wl[rl * 136 + nt * 16 + l16] = bf16r(e[nt][r] * sc);
    }
    __syncthreads();

    // coalesced uint4 stores: 64 rows x 16 uint4
    for (int c = threadIdx.x; c < 64 * 16; c += 256) {
        int r = c >> 4, cu = c & 15;
        int g = row0 + r;
        if (g < nrows) {
            uint4 vv = *(const uint4*)&Wl[r * 136 + cu * 8];
            *(uint4*)&y[(size_t)g * 128 + cu * 8] = vv;
        }
    }
}

// ---------------------------------------------------------------------------
// Fused heads: out = [mu | logsig2], X = concat(h, nodes) [rows x 256 k].
// r12 structure (validated: 50.3 -> ~28us): A direct-from-global;
// B staged in TWO 32KB XOR-swizzled K-halves (occupancy + conflict fix).
// ---------------------------------------------------------------------------
__global__ __launch_bounds__(256)
void head_mfma(const unsigned short* __restrict__ h, const float* __restrict__ nodes,
               const unsigned short* __restrict__ Wt,
               const float* __restrict__ bmu, const float* __restrict__ bls,
               float* __restrict__ out, int nrows) {
    __shared__ unsigned short Wl[128 * 128];   // 32KB K-half B tile, XOR-swizzled
    const int row0 = blockIdx.x * 64;

    const int lane = threadIdx.x & 63;
    const int w = threadIdx.x >> 6;      // wave owns rows w*16 .. w*16+15
    const int q = lane >> 4;
    const int l16 = lane & 15;
    const int grow = row0 + w * 16 + l16;
    const bool rv = (grow < nrows);

    // A fragments direct from global: 8 K-slices of 32 (h cols 0..127, nodes 128..255)
    short8 af[8];
    #pragma unroll
    for (int k0 = 0; k0 < 4; ++k0) {
        short8 z = {0, 0, 0, 0, 0, 0, 0, 0};
        if (rv) z = *(const short8*)&h[(size_t)grow * 128 + k0 * 32 + q * 8];
        af[k0] = z;
    }
    #pragma unroll
    for (int k0 = 0; k0 < 4; ++k0) {
        float4 a = make_float4(0.f, 0.f, 0.f, 0.f);
        float4 b = make_float4(0.f, 0.f, 0.f, 0.f);
        if (rv) {
            a = *(const float4*)&nodes[(size_t)grow * 128 + k0 * 32 + q * 8];
            b = *(const float4*)&nodes[(size_t)grow * 128 + k0 * 32 + q * 8 + 4];
        }
        uint4 u = make_uint4(bf16pack2(a.x, a.y), bf16pack2(a.z, a.w),
                             bf16pack2(b.x, b.y), bf16pack2(b.z, b.w));
        af[4 + k0] = *(short8*)&u;
    }

    f32x4 acc[8] = {};                   // 8 output col-blocks of 16
    #pragma unroll
    for (int half = 0; half < 2; ++half) {
        if (half) __syncthreads();       // previous half's reads done
        // stage K-half of wht (128 n x 128 k = 32KB), XOR-swizzled chunks
        for (int i = threadIdx.x; i < 128 * 16; i += 256) {
            int r = i >> 4, c = i & 15;
            *(uint4*)&Wl[r * 128 + ((c ^ (r & 7)) * 8)] =
                *(const uint4*)&Wt[r * 256 + half * 128 + c * 8];
        }
        __syncthreads();
        #pragma unroll
        for (int nt = 0; nt < 8; ++nt) {
            const int row = nt * 16 + l16;
            #pragma unroll
            for (int kk = 0; kk < 4; ++kk) {
                short8 b = *(const short8*)&Wl[row * 128 + (((kk * 4 + q) ^ (row & 7)) * 8)];
                acc[nt] = __builtin_amdgcn_mfma_f32_16x16x32_bf16(af[half * 4 + kk], b, acc[nt], 0, 0, 0);
            }
        }
    }

    // bias per col-block: nt<4 -> mu cols nt*16+l16 ; nt>=4 -> ls cols
    float bv[8];
    #pragma unroll
    for (int nt = 0; nt < 4; ++nt) bv[nt] = bmu[nt * 16 + l16];
    #pragma unroll
    for (int nt = 4; nt < 8; ++nt) bv[nt] = bls[(nt - 4) * 16 + l16];

    float* const omu = out;
    float* const ols = out + (size_t)nrows * 64;
    #pragma unroll
    for (int r = 0; r < 4; ++r) {
        const int g = row0 + w * 16 + q * 4 + r;
        if (g < nrows) {
            #pragma unroll
            for (int nt = 0; nt < 4; ++nt)
                omu[(size_t)g * 64 + nt * 16 + l16] = acc[nt][r] + bv[nt];
            #pragma unroll
            for (int nt = 4; nt < 8; ++nt)
                ols[(size_t)g * 64 + (nt - 4) * 16 + l16] = acc[nt][r] + bv[nt];
        }
    }
}

extern "C" void kernel_launch(void* const* d_in, const int* in_sizes, int n_in,
                              void* d_out, int out_size, void* d_ws, size_t ws_size,
                              hipStream_t stream) {
    const float* nodes     = (const float*)d_in[0];
    const int*   senders   = (const int*)d_in[1];
    const int*   receivers = (const int*)d_in[2];
    const float* W0  = (const float*)d_in[3];
    const float* b0  = (const float*)d_in[4];
    const float* W1  = (const float*)d_in[5];
    const float* b1  = (const float*)d_in[6];
    const float* Wmu = (const float*)d_in[7];
    const float* bmu = (const float*)d_in[8];
    const float* Wls = (const float*)d_in[9];
    const float* bls = (const float*)d_in[10];
    float* out = (float*)d_out;

    const int N = N_NODES;
    const int NT64 = (N + 63) / 64;      // 64-row tiles

    // ws: inv_s[N] f32 | inv_r[N] f32 | buf0[N*128] bf16 | buf1[N*128] bf16 | weights
    float* inv_s = (float*)d_ws;
    float* inv_r = inv_s + N;
    unsigned short* buf0 = (unsigned short*)(inv_r + N);
    unsigned short* buf1 = buf0 + (size_t)N * 128;
    unsigned short* w0t  = buf1 + (size_t)N * 128;
    unsigned short* w1t  = w0t + 128 * 128;
    unsigned short* wht  = w1t + 128 * 128;

    // sort metadata in d_out (scratch until heads write it):
    // offs[N] | deg[N] | srt[NBUCK*BCAP]  (~4MB of 51.2MB; dead before head)
    int* offs  = (int*)d_out;
    int* deg_r = offs + N;
    int* srt   = deg_r + N;

    // setup-only temps alias buf0 (dead before layer-1 writes buf0):
    // pairs[NBUCK*BCAP] uint2 (6.4MB) | sbuf[NBUCK*BCAP] (3.2MB) | gcurR[512] | gcurS[512]
    uint2* pairs = (uint2*)buf0;
    int* sbuf  = (int*)(pairs + NBUCK * BCAP);
    int* gcurR = sbuf + NBUCK * BCAP;
    int* gcurS = gcurR + 512;

    // --- single-pass reservation sort (+ fused weight prep) ---
    hipMemsetAsync(gcurR, 0, 2 * 512 * sizeof(int), stream);
    res_scatter<<<NCHUNK + 64, 1024, 0, stream>>>(receivers, senders,
                                                  W0, W1, Wmu, Wls, w0t, w1t, wht,
                                                  gcurR, gcurS, pairs, sbuf);
    bucket_final2<<<2 * NBUCK, 256, 0, stream>>>(pairs, sbuf, gcurR, gcurS,
                                                 offs, deg_r, srt, inv_r, inv_s, N);

    // --- layer 1 ---
    gc_mfma<false><<<NT64, 256, 0, stream>>>(nodes, w0t, b0, inv_s, buf0, N);
    aggregate_kernel<<<2048, 256, 0, stream>>>((const uint4*)buf0, (uint4*)buf1,
                                               offs, deg_r, srt, inv_r, N);

    // --- layer 2 (input pre-scaled bf16) ---
    gc_mfma<true><<<NT64, 256, 0, stream>>>(buf1, w1t, b1, inv_s, buf0, N);
    aggregate_kernel<<<2048, 256, 0, stream>>>((const uint4*)buf0, (uint4*)buf1,
                                               offs, deg_r, srt, inv_r, N);

    // --- fused heads: out = [mu | logsig2] ---
    head_mfma<<<NT64, 256, 0, stream>>>(buf1, nodes, wht, bmu, bls, out, N);
}